// Round 7
// baseline (1242.571 us; speedup 1.0000x reference)
//
#include <hip/hip_runtime.h>
#include <hip/hip_bf16.h>
#include <math.h>

#define N_NODES 100000
#define N_EDGES 1000000
#define HALF_E  500000
#define H       128
#define NG      256
#define RELROWS 201
#define NH      (N_NODES * H)
#define SCAN_NB 98   // 98 * 1024 >= 100000
#define XPITCH  136  // 128 + 8 bf16 pad (breaks LDS bank aliasing)
#define MMB     64   // X rows per mm block

typedef __attribute__((ext_vector_type(8))) short bf16x8;
typedef __attribute__((ext_vector_type(4))) float f32x4;

// ---- bf16 pack/unpack helpers (RNE) ----
__device__ __forceinline__ float bflo(unsigned p) { return __uint_as_float(p << 16); }
__device__ __forceinline__ float bfhi(unsigned p) { return __uint_as_float(p & 0xffff0000u); }
__device__ __forceinline__ unsigned packbf2(float a, float b) {
    unsigned ua = __float_as_uint(a), ub = __float_as_uint(b);
    ua = (ua + 0x7fffu + ((ua >> 16) & 1u)) >> 16;
    ub = (ub + 0x7fffu + ((ub >> 16) & 1u)) >> 16;
    return ua | (ub << 16);
}
__device__ __forceinline__ unsigned short packbf1(float a) {
    unsigned ua = __float_as_uint(a);
    return (unsigned short)((ua + 0x7fffu + ((ua >> 16) & 1u)) >> 16);
}

// ---------------- degree (per-direction, over src) + dst histogram ----------------
__global__ void deg_hist_kernel(const int* __restrict__ ei, float* deg_in, float* deg_out,
                                int* __restrict__ cnt_dst) {
    int e = blockIdx.x * 256 + threadIdx.x;
    if (e >= N_EDGES) return;
    int src = ei[e];
    int dst = ei[N_EDGES + e];
    if (e < HALF_E) atomicAdd(deg_in + src, 1.0f);
    else            atomicAdd(deg_out + src, 1.0f);
    atomicAdd(cnt_dst + dst, 1);
}

__global__ void dinv_kernel(float* a, float* b) {
    int i = blockIdx.x * 256 + threadIdx.x;
    if (i >= N_NODES) return;
    float d = a[i]; a[i] = d > 0.f ? rsqrtf(d) : 0.f;
    d = b[i];       b[i] = d > 0.f ? rsqrtf(d) : 0.f;
}

// ---------------- 3-phase exclusive scan over cnt_dst ----------------
__global__ __launch_bounds__(1024) void scan1_kernel(const int* __restrict__ cnt,
                                                     int* __restrict__ excl,
                                                     int* __restrict__ bsum) {
    __shared__ int ps[1024];
    int t = threadIdx.x;
    int i = blockIdx.x * 1024 + t;
    int v = (i < N_NODES) ? cnt[i] : 0;
    ps[t] = v;
    __syncthreads();
    for (int off = 1; off < 1024; off <<= 1) {
        int u = (t >= off) ? ps[t - off] : 0;
        __syncthreads();
        ps[t] += u;
        __syncthreads();
    }
    if (i < N_NODES) excl[i] = ps[t] - v;
    if (t == 1023) bsum[blockIdx.x] = ps[t];
}

__global__ __launch_bounds__(128) void scan2_kernel(const int* __restrict__ bsum,
                                                    int* __restrict__ boff,
                                                    int* __restrict__ rowptr) {
    __shared__ int ps[128];
    int t = threadIdx.x;
    int v = (t < SCAN_NB) ? bsum[t] : 0;
    ps[t] = v;
    __syncthreads();
    for (int off = 1; off < 128; off <<= 1) {
        int u = (t >= off) ? ps[t - off] : 0;
        __syncthreads();
        ps[t] += u;
        __syncthreads();
    }
    if (t < SCAN_NB) boff[t] = ps[t] - v;
    if (t == 127) rowptr[N_NODES] = ps[t];
}

__global__ __launch_bounds__(1024) void scan3_kernel(const int* __restrict__ excl,
                                                     const int* __restrict__ boff,
                                                     int* __restrict__ rowptr,
                                                     int* __restrict__ rfill) {
    int t = threadIdx.x;
    int i = blockIdx.x * 1024 + t;
    if (i >= N_NODES) return;
    int r = excl[i] + boff[blockIdx.x];
    rowptr[i] = r;
    rfill[i] = r;
}

// ---------------- fill CSR: mn = { (src + dir*N) | ((typ + dir*200) << 18), bits(norm) } ----------------
__global__ void fill_kernel(const int* __restrict__ ei, const int* __restrict__ etype,
                            const float* __restrict__ dinv_in, const float* __restrict__ dinv_out,
                            int* __restrict__ rfill, int2* __restrict__ csr_mn) {
    int e = blockIdx.x * 256 + threadIdx.x;
    if (e >= N_EDGES) return;
    int s = ei[e], d = ei[N_EDGES + e];
    int t = etype[e];
    bool isin = (e < HALF_E);
    const float* dv = isin ? dinv_in : dinv_out;
    float nv = dv[s] * dv[d];
    int j = atomicAdd(rfill + d, 1);
    int src2 = s + (isin ? 0 : N_NODES);
    int typ2 = t + (isin ? 0 : 200);
    csr_mn[j] = make_int2(src2 | (typ2 << 18), __float_as_int(nv));
}

// ---------------- per-graph node counts via binary search (batch is sorted) ----------------
__global__ void cnt_bs_kernel(const int* __restrict__ batch, float* __restrict__ cnt) {
    int g = blockIdx.x * 64 + threadIdx.x;
    if (g >= NG) return;
    int lo = 0, hi = N_NODES;
    while (lo < hi) { int mid = (lo + hi) >> 1; if (batch[mid] < g) lo = mid + 1; else hi = mid; }
    int start = lo;
    lo = 0; hi = N_NODES;
    while (lo < hi) { int mid = (lo + hi) >> 1; if (batch[mid] < g + 1) lo = mid + 1; else hi = mid; }
    cnt[g] = (float)(lo - start);
}

// ---------------- rel chain (tiny) ----------------
__global__ void rel_build_kernel(const float* __restrict__ rge, const float* __restrict__ rbuf,
                                 const float* __restrict__ loop_rel, float* __restrict__ relA, int layer) {
    int i = blockIdx.x;      // 0..200
    int j = threadIdx.x;     // 0..127
    float v;
    if (i == 200)          v = loop_rel[j];
    else if (layer == 1)   v = (i < 100) ? rge[i * H + j] : -rge[(i - 100) * H + j];
    else                   v = rbuf[i * H + j];
    relA[i * H + j] = v;
}

// RWh layout per layer (bf16): rows 0..199 = rel@w_in, rows 200..399 = rel@w_out
__global__ void rel_mm_kernel(const float* __restrict__ relA,
                              const float* __restrict__ wIn, const float* __restrict__ wOut,
                              const float* __restrict__ wRel, const float* __restrict__ wLoop,
                              unsigned short* __restrict__ RWh, float* __restrict__ rbuf,
                              float* __restrict__ lwl) {
    __shared__ float a[H];
    int i = blockIdx.x, j = threadIdx.x;
    a[j] = relA[i * H + j];
    __syncthreads();
    float s_in = 0.f, s_out = 0.f, s_rel = 0.f, s_loop = 0.f;
    for (int k = 0; k < H; k++) {
        float av = a[k];
        s_in  += av * wIn [k * H + j];
        s_out += av * wOut[k * H + j];
        s_rel += av * wRel[k * H + j];
        s_loop += av * wLoop[k * H + j];
    }
    if (i < 200) {
        RWh[i * H + j] = packbf1(s_in);
        RWh[(200 + i) * H + j] = packbf1(s_out);
        rbuf[i * H + j] = s_rel;
    }
    if (i == 200) lwl[j] = s_loop;
}

// ---------------- weight pre-pack into MFMA B-fragment order (bf16) ----------------
struct WPtrs { const float* p[9]; };
__global__ __launch_bounds__(256) void wpack_kernel(WPtrs wp, unsigned short* __restrict__ Bp) {
    int iw = blockIdx.y;  // l*3 + w
    const float* W = wp.p[iw];
    unsigned short* out = Bp + (size_t)iw * 16384;
    int t = blockIdx.x * 256 + threadIdx.x;   // 0..2047
    int nt = t >> 8, kk = (t >> 6) & 3, lane = t & 63;
    int n = nt * 16 + (lane & 15);
    int k0 = kk * 32 + (lane >> 4) * 8;
    unsigned p[4];
    for (int j = 0; j < 4; j++)
        p[j] = packbf2(W[(k0 + 2 * j) * H + n], W[(k0 + 2 * j + 1) * H + n]);
    *(uint4*)(out + ((size_t)(nt * 4 + kk) * 64 + lane) * 8) = make_uint4(p[0], p[1], p[2], p[3]);
}

// ---------------- MFMA node matmuls: Qh=X@wIn, Rh=X@wOut (bf16), Sb=X@wLoop - lwl (bf16) ----------------
__global__ __launch_bounds__(256) void mm_mfma_kernel(const float* __restrict__ Xf,
                                                      const unsigned short* __restrict__ Xh,
                                                      int xf32,
                                                      const unsigned short* __restrict__ Bpack,
                                                      const float* __restrict__ lwl,
                                                      unsigned short* __restrict__ QRh,
                                                      unsigned short* __restrict__ Sb) {
    __shared__ unsigned short xt[MMB * XPITCH];
    int tid = threadIdx.x;
    int row0 = blockIdx.x * MMB;
    int nrows = min(MMB, N_NODES - row0);
    if (xf32) {
        for (int t = 0; t < 8; t++) {
            int idx = tid + t * 256;                 // 2048 float4s
            int r = idx >> 5, c4 = (idx & 31) * 4;
            if (r < nrows) {
                float4 v = *(const float4*)(Xf + (size_t)(row0 + r) * H + c4);
                *(uint2*)(xt + r * XPITCH + c4) = make_uint2(packbf2(v.x, v.y), packbf2(v.z, v.w));
            }
        }
    } else {
        for (int t = 0; t < 4; t++) {
            int idx = tid + t * 256;                 // 1024 uint4s (8 bf16 each)
            int r = idx >> 4, c8 = (idx & 15) * 8;
            if (r < nrows)
                *(uint4*)(xt + r * XPITCH + c8) = *(const uint4*)(Xh + (size_t)(row0 + r) * H + c8);
        }
    }
    __syncthreads();

    int wave = tid >> 6, lane = tid & 63;
    int m0w = wave * 16;
    int q = lane >> 4, ml = lane & 15;
    bf16x8 afrag[4];
    for (int kk = 0; kk < 4; kk++)
        afrag[kk] = *(const bf16x8*)(xt + (m0w + ml) * XPITCH + kk * 32 + q * 8);
    int grow_base = row0 + m0w + q * 4;
    for (int w = 0; w < 3; w++) {
        for (int nt = 0; nt < 8; nt++) {
            const unsigned short* bp = Bpack + (((size_t)(w * 8 + nt) * 4) * 64 + lane) * 8;
            f32x4 acc = {0.f, 0.f, 0.f, 0.f};
            for (int kk = 0; kk < 4; kk++) {
                bf16x8 bfrag = *(const bf16x8*)(bp + (size_t)kk * 512);
                acc = __builtin_amdgcn_mfma_f32_16x16x32_bf16(afrag[kk], bfrag, acc, 0, 0, 0);
            }
            int col = nt * 16 + ml;
            if (w < 2) {
                size_t rbase = (w == 0) ? 0 : (size_t)N_NODES;
                for (int reg = 0; reg < 4; reg++) {
                    int grow = grow_base + reg;
                    if (grow < N_NODES)
                        QRh[(rbase + grow) * H + col] = packbf1(acc[reg]);
                }
            } else {
                float sub = lwl[col];
                for (int reg = 0; reg < 4; reg++) {
                    int grow = grow_base + reg;
                    if (grow < N_NODES)
                        Sb[(size_t)grow * H + col] = packbf1(acc[reg] - sub);
                }
            }
        }
    }
}

// ---------------- gather + combine: 16 lanes per dst node, 4 nodes per wave ----------------
#define ACC8(qv, rv, n) \
    acc[0] += (bflo(qv.x) - bflo(rv.x)) * n; acc[1] += (bfhi(qv.x) - bfhi(rv.x)) * n; \
    acc[2] += (bflo(qv.y) - bflo(rv.y)) * n; acc[3] += (bfhi(qv.y) - bfhi(rv.y)) * n; \
    acc[4] += (bflo(qv.z) - bflo(rv.z)) * n; acc[5] += (bfhi(qv.z) - bfhi(rv.z)) * n; \
    acc[6] += (bflo(qv.w) - bflo(rv.w)) * n; acc[7] += (bfhi(qv.w) - bfhi(rv.w)) * n;

__global__ __launch_bounds__(256) void gather_kernel(const int* __restrict__ rowptr,
                                                     const int2* __restrict__ csr_mn,
                                                     const unsigned* __restrict__ QRh,
                                                     const unsigned* __restrict__ RWh,
                                                     const float* __restrict__ b,
                                                     unsigned* __restrict__ Sb,
                                                     const int* __restrict__ batch,
                                                     float* __restrict__ pool, int mode) {
    int tid = threadIdx.x;
    int wave = tid >> 6, lane = tid & 63;
    int sub = lane >> 4, sl = lane & 15;
    int v = blockIdx.x * 16 + wave * 4 + sub;
    if (v >= N_NODES) return;
    int jb = rowptr[v], je = rowptr[v + 1];
    uint4 sv = *(const uint4*)(Sb + (size_t)v * 64 + sl * 4);
    float acc[8];
    acc[0] = bflo(sv.x); acc[1] = bfhi(sv.x);
    acc[2] = bflo(sv.y); acc[3] = bfhi(sv.y);
    acc[4] = bflo(sv.z); acc[5] = bfhi(sv.z);
    acc[6] = bflo(sv.w); acc[7] = bfhi(sv.w);
    int j = jb;
    for (; j + 1 < je; j += 2) {
        int2 mn0 = csr_mn[j], mn1 = csr_mn[j + 1];
        uint4 q0 = *(const uint4*)(QRh + (size_t)(mn0.x & 0x3FFFF) * 64 + sl * 4);
        uint4 r0 = *(const uint4*)(RWh + (size_t)((unsigned)mn0.x >> 18) * 64 + sl * 4);
        uint4 q1 = *(const uint4*)(QRh + (size_t)(mn1.x & 0x3FFFF) * 64 + sl * 4);
        uint4 r1 = *(const uint4*)(RWh + (size_t)((unsigned)mn1.x >> 18) * 64 + sl * 4);
        float n0 = __int_as_float(mn0.y), n1 = __int_as_float(mn1.y);
        ACC8(q0, r0, n0)
        ACC8(q1, r1, n1)
    }
    if (j < je) {
        int2 mn0 = csr_mn[j];
        uint4 q0 = *(const uint4*)(QRh + (size_t)(mn0.x & 0x3FFFF) * 64 + sl * 4);
        uint4 r0 = *(const uint4*)(RWh + (size_t)((unsigned)mn0.x >> 18) * 64 + sl * 4);
        float n0 = __int_as_float(mn0.y);
        ACC8(q0, r0, n0)
    }
    int c0 = sl * 8;
    float vv[8];
    for (int k = 0; k < 8; k++)
        vv[k] = tanhf(acc[k] * (1.f / 3.f) + b[c0 + k]);
    if (mode == 0) {
        for (int k = 0; k < 8; k++) vv[k] = fmaxf(vv[k], 0.f);
        uint4 o = make_uint4(packbf2(vv[0], vv[1]), packbf2(vv[2], vv[3]),
                             packbf2(vv[4], vv[5]), packbf2(vv[6], vv[7]));
        *(uint4*)(Sb + (size_t)v * 64 + sl * 4) = o;
    } else {
        int g = batch[v];
        for (int k = 0; k < 8; k++)
            atomicAdd(pool + g * H + c0 + k, vv[k]);
    }
}

// ---------------- final: out[g] = [mean, rel_emb] @ lin_w + lin_b ----------------
__global__ void final_kernel(const float* __restrict__ pool, const float* __restrict__ cnt,
                             const float* __restrict__ rel_table, const int* __restrict__ rel_labels,
                             const float* __restrict__ lin_w, const float* __restrict__ lin_b,
                             float* __restrict__ out) {
    int g = blockIdx.x;
    int lane = threadIdx.x;   // 64
    float inv = 1.f / fmaxf(cnt[g], 1.f);
    const float* rrow = rel_table + (size_t)rel_labels[g] * H;
    float p0 = 0.f, p1 = 0.f;
    for (int c = lane; c < H; c += 64) {
        float m = pool[g * H + c] * inv;
        p0 += m * lin_w[c * 2 + 0];
        p1 += m * lin_w[c * 2 + 1];
        float rv = rrow[c];
        p0 += rv * lin_w[(H + c) * 2 + 0];
        p1 += rv * lin_w[(H + c) * 2 + 1];
    }
    for (int off = 32; off; off >>= 1) {
        p0 += __shfl_down(p0, off);
        p1 += __shfl_down(p1, off);
    }
    if (lane == 0) {
        out[g * 2 + 0] = p0 + lin_b[0];
        out[g * 2 + 1] = p1 + lin_b[1];
    }
}

extern "C" void kernel_launch(void* const* d_in, const int* in_sizes, int n_in,
                              void* d_out, int out_size, void* d_ws, size_t ws_size,
                              hipStream_t stream) {
    const float* x          = (const float*)d_in[0];
    const int*   ei         = (const int*)  d_in[1];
    const int*   etype      = (const int*)  d_in[2];
    const int*   batch      = (const int*)  d_in[3];
    const int*   rel_labels = (const int*)  d_in[4];
    const float* rel_table  = (const float*)d_in[6];
    const float* rge        = (const float*)d_in[7];
    const float* lin_w      = (const float*)d_in[26];
    const float* lin_b      = (const float*)d_in[27];
    float* out = (float*)d_out;

    // ---- workspace layout (regions padded to 16 B) ----
    float* ws       = (float*)d_ws;
    float* dinv_in  = ws;                    // N
    float* dinv_out = dinv_in + N_NODES;     // N
    float* pool     = dinv_out + N_NODES;    // NG*H
    float* cnt      = pool + NG * H;         // NG
    float* relA     = cnt + NG;              // 201*H
    float* rbuf     = relA + RELROWS * H;    // 200*H
    float* lwl      = rbuf + 200 * H;        // 3*H
    int*   rowptr   = (int*)(lwl + 3 * H);   // N+1 (pad to N+4)
    int*   rfill    = rowptr + N_NODES + 4;  // N
    int*   cnt_dst  = rfill + N_NODES;       // N
    int*   excl     = cnt_dst + N_NODES;     // N
    int*   bsum     = excl + N_NODES;        // SCAN_NB (pad 100)
    int*   boff     = bsum + 100;            // SCAN_NB (pad 100)
    int2*  csr_mn   = (int2*)(boff + 100);   // E int2
    unsigned* QRh   = (unsigned*)(csr_mn + N_EDGES);   // NH uints (Q rows, then R rows)
    unsigned* Sb    = QRh + (size_t)NH;                // NH/2 uints (N x 128 bf16)
    unsigned* RWh   = Sb + (size_t)NH / 2;             // 3*400*64 uints
    unsigned short* Bpack = (unsigned short*)(RWh + 3 * 400 * 64);  // 9*16384 bf16

    hipMemsetAsync(dinv_in, 0, (size_t)(2 * N_NODES + NG * H + NG) * sizeof(float), stream);
    hipMemsetAsync(cnt_dst, 0, (size_t)N_NODES * sizeof(int), stream);

    deg_hist_kernel<<<(N_EDGES + 255) / 256, 256, 0, stream>>>(ei, dinv_in, dinv_out, cnt_dst);
    dinv_kernel    <<<(N_NODES + 255) / 256, 256, 0, stream>>>(dinv_in, dinv_out);
    scan1_kernel   <<<SCAN_NB, 1024, 0, stream>>>(cnt_dst, excl, bsum);
    scan2_kernel   <<<1, 128, 0, stream>>>(bsum, boff, rowptr);
    scan3_kernel   <<<SCAN_NB, 1024, 0, stream>>>(excl, boff, rowptr, rfill);
    fill_kernel    <<<(N_EDGES + 255) / 256, 256, 0, stream>>>(ei, etype, dinv_in, dinv_out,
                                                               rfill, csr_mn);
    cnt_bs_kernel  <<<NG / 64, 64, 0, stream>>>(batch, cnt);

    // pack all 9 weight matrices into MFMA B-frag order
    WPtrs wp;
    for (int l = 0; l < 3; l++) {
        wp.p[l * 3 + 0] = (const float*)d_in[8 + 6 * l + 0];  // wIn
        wp.p[l * 3 + 1] = (const float*)d_in[8 + 6 * l + 1];  // wOut
        wp.p[l * 3 + 2] = (const float*)d_in[8 + 6 * l + 2];  // wLoop
    }
    wpack_kernel<<<dim3(8, 9), 256, 0, stream>>>(wp, Bpack);

    // rel chain up-front
    for (int l = 0; l < 3; l++) {
        const float* wIn   = (const float*)d_in[8 + 6 * l + 0];
        const float* wOut  = (const float*)d_in[8 + 6 * l + 1];
        const float* wLoop = (const float*)d_in[8 + 6 * l + 2];
        const float* wRel  = (const float*)d_in[8 + 6 * l + 3];
        const float* lrel  = (const float*)d_in[8 + 6 * l + 4];
        rel_build_kernel<<<RELROWS, H, 0, stream>>>(rge, rbuf, lrel, relA, l + 1);
        rel_mm_kernel   <<<RELROWS, H, 0, stream>>>(relA, wIn, wOut, wRel, wLoop,
                                                    (unsigned short*)(RWh + (size_t)l * 400 * 64),
                                                    rbuf, lwl + l * H);
    }

    // three conv layers
    int mm_grid = (N_NODES + MMB - 1) / MMB;
    for (int l = 0; l < 3; l++) {
        const float* bl = (const float*)d_in[8 + 6 * l + 5];
        mm_mfma_kernel<<<mm_grid, 256, 0, stream>>>(x, (const unsigned short*)Sb, (l == 0) ? 1 : 0,
                                                    Bpack + (size_t)l * 3 * 16384, lwl + l * H,
                                                    (unsigned short*)QRh, (unsigned short*)Sb);
        gather_kernel<<<N_NODES / 16, 256, 0, stream>>>(rowptr, csr_mn,
                                                        QRh, RWh + (size_t)l * 400 * 64, bl,
                                                        Sb, batch, pool, (l == 2) ? 1 : 0);
    }

    final_kernel<<<NG, 64, 0, stream>>>(pool, cnt, rel_table, rel_labels, lin_w, lin_b, out);
}

// Round 8
// 743.768 us; speedup vs baseline: 1.6706x; 1.6706x over previous
//
#include <hip/hip_runtime.h>
#include <hip/hip_bf16.h>
#include <math.h>

#define N_NODES 100000
#define N_EDGES 1000000
#define HALF_E  500000
#define H       128
#define NG      256
#define RELROWS 201
#define NH      (N_NODES * H)
#define SCAN_NB 98   // 98 * 1024 >= 100000
#define XPITCH  136  // 128 + 8 bf16 pad (breaks LDS bank aliasing)
#define MMB     64   // X rows per mm block

typedef __attribute__((ext_vector_type(8))) short bf16x8;
typedef __attribute__((ext_vector_type(4))) float f32x4;

// ---- bf16 pack/unpack helpers (RNE) ----
__device__ __forceinline__ float bflo(unsigned p) { return __uint_as_float(p << 16); }
__device__ __forceinline__ float bfhi(unsigned p) { return __uint_as_float(p & 0xffff0000u); }
__device__ __forceinline__ unsigned packbf2(float a, float b) {
    unsigned ua = __float_as_uint(a), ub = __float_as_uint(b);
    ua = (ua + 0x7fffu + ((ua >> 16) & 1u)) >> 16;
    ub = (ub + 0x7fffu + ((ub >> 16) & 1u)) >> 16;
    return ua | (ub << 16);
}
__device__ __forceinline__ unsigned short packbf1(float a) {
    unsigned ua = __float_as_uint(a);
    return (unsigned short)((ua + 0x7fffu + ((ua >> 16) & 1u)) >> 16);
}

// ---------------- degree (per-direction, over src) + dst histogram ----------------
__global__ void deg_hist_kernel(const int* __restrict__ ei, float* deg_in, float* deg_out,
                                int* __restrict__ cnt_dst) {
    int e = blockIdx.x * 256 + threadIdx.x;
    if (e >= N_EDGES) return;
    int src = ei[e];
    int dst = ei[N_EDGES + e];
    if (e < HALF_E) atomicAdd(deg_in + src, 1.0f);
    else            atomicAdd(deg_out + src, 1.0f);
    atomicAdd(cnt_dst + dst, 1);
}

__global__ void dinv_kernel(float* a, float* b) {
    int i = blockIdx.x * 256 + threadIdx.x;
    if (i >= N_NODES) return;
    float d = a[i]; a[i] = d > 0.f ? rsqrtf(d) : 0.f;
    d = b[i];       b[i] = d > 0.f ? rsqrtf(d) : 0.f;
}

// ---------------- 3-phase exclusive scan over cnt_dst ----------------
__global__ __launch_bounds__(1024) void scan1_kernel(const int* __restrict__ cnt,
                                                     int* __restrict__ excl,
                                                     int* __restrict__ bsum) {
    __shared__ int ps[1024];
    int t = threadIdx.x;
    int i = blockIdx.x * 1024 + t;
    int v = (i < N_NODES) ? cnt[i] : 0;
    ps[t] = v;
    __syncthreads();
    for (int off = 1; off < 1024; off <<= 1) {
        int u = (t >= off) ? ps[t - off] : 0;
        __syncthreads();
        ps[t] += u;
        __syncthreads();
    }
    if (i < N_NODES) excl[i] = ps[t] - v;
    if (t == 1023) bsum[blockIdx.x] = ps[t];
}

__global__ __launch_bounds__(128) void scan2_kernel(const int* __restrict__ bsum,
                                                    int* __restrict__ boff,
                                                    int* __restrict__ rowptr) {
    __shared__ int ps[128];
    int t = threadIdx.x;
    int v = (t < SCAN_NB) ? bsum[t] : 0;
    ps[t] = v;
    __syncthreads();
    for (int off = 1; off < 128; off <<= 1) {
        int u = (t >= off) ? ps[t - off] : 0;
        __syncthreads();
        ps[t] += u;
        __syncthreads();
    }
    if (t < SCAN_NB) boff[t] = ps[t] - v;
    if (t == 127) rowptr[N_NODES] = ps[t];
}

__global__ __launch_bounds__(1024) void scan3_kernel(const int* __restrict__ excl,
                                                     const int* __restrict__ boff,
                                                     int* __restrict__ rowptr,
                                                     int* __restrict__ rfill) {
    int t = threadIdx.x;
    int i = blockIdx.x * 1024 + t;
    if (i >= N_NODES) return;
    int r = excl[i] + boff[blockIdx.x];
    rowptr[i] = r;
    rfill[i] = r;
}

// ---------------- fill CSR: mn = { (src + dir*N) | ((typ + dir*200) << 18), bits(norm) } ----------------
__global__ void fill_kernel(const int* __restrict__ ei, const int* __restrict__ etype,
                            const float* __restrict__ dinv_in, const float* __restrict__ dinv_out,
                            int* __restrict__ rfill, int2* __restrict__ csr_mn) {
    int e = blockIdx.x * 256 + threadIdx.x;
    if (e >= N_EDGES) return;
    int s = ei[e], d = ei[N_EDGES + e];
    int t = etype[e];
    bool isin = (e < HALF_E);
    const float* dv = isin ? dinv_in : dinv_out;
    float nv = dv[s] * dv[d];
    int j = atomicAdd(rfill + d, 1);
    int src2 = s + (isin ? 0 : N_NODES);
    int typ2 = t + (isin ? 0 : 200);
    csr_mn[j] = make_int2(src2 | (typ2 << 18), __float_as_int(nv));
}

// ---------------- per-graph node counts via binary search (batch is sorted) ----------------
__global__ void cnt_bs_kernel(const int* __restrict__ batch, float* __restrict__ cnt) {
    int g = blockIdx.x * 64 + threadIdx.x;
    if (g >= NG) return;
    int lo = 0, hi = N_NODES;
    while (lo < hi) { int mid = (lo + hi) >> 1; if (batch[mid] < g) lo = mid + 1; else hi = mid; }
    int start = lo;
    lo = 0; hi = N_NODES;
    while (lo < hi) { int mid = (lo + hi) >> 1; if (batch[mid] < g + 1) lo = mid + 1; else hi = mid; }
    cnt[g] = (float)(lo - start);
}

// ---------------- rel chain (tiny) ----------------
__global__ void rel_build_kernel(const float* __restrict__ rge, const float* __restrict__ rbuf,
                                 const float* __restrict__ loop_rel, float* __restrict__ relA, int layer) {
    int i = blockIdx.x;      // 0..200
    int j = threadIdx.x;     // 0..127
    float v;
    if (i == 200)          v = loop_rel[j];
    else if (layer == 1)   v = (i < 100) ? rge[i * H + j] : -rge[(i - 100) * H + j];
    else                   v = rbuf[i * H + j];
    relA[i * H + j] = v;
}

// RWh layout per layer (bf16): rows 0..199 = rel@w_in, rows 200..399 = rel@w_out
__global__ void rel_mm_kernel(const float* __restrict__ relA,
                              const float* __restrict__ wIn, const float* __restrict__ wOut,
                              const float* __restrict__ wRel, const float* __restrict__ wLoop,
                              unsigned short* __restrict__ RWh, float* __restrict__ rbuf,
                              float* __restrict__ lwl) {
    __shared__ float a[H];
    int i = blockIdx.x, j = threadIdx.x;
    a[j] = relA[i * H + j];
    __syncthreads();
    float s_in = 0.f, s_out = 0.f, s_rel = 0.f, s_loop = 0.f;
    for (int k = 0; k < H; k++) {
        float av = a[k];
        s_in  += av * wIn [k * H + j];
        s_out += av * wOut[k * H + j];
        s_rel += av * wRel[k * H + j];
        s_loop += av * wLoop[k * H + j];
    }
    if (i < 200) {
        RWh[i * H + j] = packbf1(s_in);
        RWh[(200 + i) * H + j] = packbf1(s_out);
        rbuf[i * H + j] = s_rel;
    }
    if (i == 200) lwl[j] = s_loop;
}

// ---------------- weight pre-pack into MFMA B-fragment order (bf16) ----------------
struct WPtrs { const float* p[9]; };
__global__ __launch_bounds__(256) void wpack_kernel(WPtrs wp, unsigned short* __restrict__ Bp) {
    int iw = blockIdx.y;  // l*3 + w
    const float* W = wp.p[iw];
    unsigned short* out = Bp + (size_t)iw * 16384;
    int t = blockIdx.x * 256 + threadIdx.x;   // 0..2047
    int nt = t >> 8, kk = (t >> 6) & 3, lane = t & 63;
    int n = nt * 16 + (lane & 15);
    int k0 = kk * 32 + (lane >> 4) * 8;
    unsigned p[4];
    for (int j = 0; j < 4; j++)
        p[j] = packbf2(W[(k0 + 2 * j) * H + n], W[(k0 + 2 * j + 1) * H + n]);
    *(uint4*)(out + ((size_t)(nt * 4 + kk) * 64 + lane) * 8) = make_uint4(p[0], p[1], p[2], p[3]);
}

// ---------------- MFMA node matmuls: Qh=X@wIn, Rh=X@wOut (bf16), Sb=X@wLoop - lwl (bf16) ----------------
__global__ __launch_bounds__(256) void mm_mfma_kernel(const float* __restrict__ Xf,
                                                      const unsigned short* __restrict__ Xh,
                                                      int xf32,
                                                      const unsigned short* __restrict__ Bpack,
                                                      const float* __restrict__ lwl,
                                                      unsigned short* __restrict__ QRh,
                                                      unsigned short* __restrict__ Sb) {
    __shared__ unsigned short xt[MMB * XPITCH];
    int tid = threadIdx.x;
    int row0 = blockIdx.x * MMB;
    int nrows = min(MMB, N_NODES - row0);
    if (xf32) {
        for (int t = 0; t < 8; t++) {
            int idx = tid + t * 256;                 // 2048 float4s
            int r = idx >> 5, c4 = (idx & 31) * 4;
            if (r < nrows) {
                float4 v = *(const float4*)(Xf + (size_t)(row0 + r) * H + c4);
                *(uint2*)(xt + r * XPITCH + c4) = make_uint2(packbf2(v.x, v.y), packbf2(v.z, v.w));
            }
        }
    } else {
        for (int t = 0; t < 4; t++) {
            int idx = tid + t * 256;                 // 1024 uint4s (8 bf16 each)
            int r = idx >> 4, c8 = (idx & 15) * 8;
            if (r < nrows)
                *(uint4*)(xt + r * XPITCH + c8) = *(const uint4*)(Xh + (size_t)(row0 + r) * H + c8);
        }
    }
    __syncthreads();

    int wave = tid >> 6, lane = tid & 63;
    int m0w = wave * 16;
    int q = lane >> 4, ml = lane & 15;
    bf16x8 afrag[4];
    for (int kk = 0; kk < 4; kk++)
        afrag[kk] = *(const bf16x8*)(xt + (m0w + ml) * XPITCH + kk * 32 + q * 8);
    int grow_base = row0 + m0w + q * 4;
    for (int w = 0; w < 3; w++) {
        for (int nt = 0; nt < 8; nt++) {
            const unsigned short* bp = Bpack + (((size_t)(w * 8 + nt) * 4) * 64 + lane) * 8;
            f32x4 acc = {0.f, 0.f, 0.f, 0.f};
            for (int kk = 0; kk < 4; kk++) {
                bf16x8 bfrag = *(const bf16x8*)(bp + (size_t)kk * 512);
                acc = __builtin_amdgcn_mfma_f32_16x16x32_bf16(afrag[kk], bfrag, acc, 0, 0, 0);
            }
            int col = nt * 16 + ml;
            if (w < 2) {
                size_t rbase = (w == 0) ? 0 : (size_t)N_NODES;
                for (int reg = 0; reg < 4; reg++) {
                    int grow = grow_base + reg;
                    if (grow < N_NODES)
                        QRh[(rbase + grow) * H + col] = packbf1(acc[reg]);
                }
            } else {
                float sub = lwl[col];
                for (int reg = 0; reg < 4; reg++) {
                    int grow = grow_base + reg;
                    if (grow < N_NODES)
                        Sb[(size_t)grow * H + col] = packbf1(acc[reg] - sub);
                }
            }
        }
    }
}

// ---------------- gather + combine: one wave per dst node, dword loads, 8x unroll ----------------
__global__ __launch_bounds__(256) void gather_kernel(const int* __restrict__ rowptr,
                                                     const int2* __restrict__ csr_mn,
                                                     const unsigned* __restrict__ QRh,
                                                     const unsigned* __restrict__ RWh,
                                                     const float* __restrict__ b,
                                                     unsigned* __restrict__ Sb,
                                                     const int* __restrict__ batch,
                                                     float* __restrict__ pool, int mode) {
    int v = blockIdx.x * 4 + (threadIdx.x >> 6);
    if (v >= N_NODES) return;
    int lane = threadIdx.x & 63;
    int c = lane * 2;
    int jb = rowptr[v], je = rowptr[v + 1];
    unsigned sv = Sb[(size_t)v * 64 + lane];
    float ax = bflo(sv), ay = bfhi(sv);   // loop term
    int j = jb;
    for (; j + 7 < je; j += 8) {
        int2 mn[8];
        #pragma unroll
        for (int k = 0; k < 8; k++) mn[k] = csr_mn[j + k];
        unsigned q[8], r[8];
        #pragma unroll
        for (int k = 0; k < 8; k++) {
            q[k] = QRh[(size_t)(mn[k].x & 0x3FFFF) * 64 + lane];
            r[k] = RWh[(size_t)((unsigned)mn[k].x >> 18) * 64 + lane];
        }
        #pragma unroll
        for (int k = 0; k < 8; k++) {
            float n = __int_as_float(mn[k].y);
            ax += (bflo(q[k]) - bflo(r[k])) * n;
            ay += (bfhi(q[k]) - bfhi(r[k])) * n;
        }
    }
    for (; j + 1 < je; j += 2) {
        int2 mn0 = csr_mn[j], mn1 = csr_mn[j + 1];
        unsigned q0 = QRh[(size_t)(mn0.x & 0x3FFFF) * 64 + lane];
        unsigned r0 = RWh[(size_t)((unsigned)mn0.x >> 18) * 64 + lane];
        unsigned q1 = QRh[(size_t)(mn1.x & 0x3FFFF) * 64 + lane];
        unsigned r1 = RWh[(size_t)((unsigned)mn1.x >> 18) * 64 + lane];
        float n0 = __int_as_float(mn0.y), n1 = __int_as_float(mn1.y);
        ax += (bflo(q0) - bflo(r0)) * n0; ay += (bfhi(q0) - bfhi(r0)) * n0;
        ax += (bflo(q1) - bflo(r1)) * n1; ay += (bfhi(q1) - bfhi(r1)) * n1;
    }
    if (j < je) {
        int2 mn0 = csr_mn[j];
        float n0 = __int_as_float(mn0.y);
        unsigned q0 = QRh[(size_t)(mn0.x & 0x3FFFF) * 64 + lane];
        unsigned r0 = RWh[(size_t)((unsigned)mn0.x >> 18) * 64 + lane];
        ax += (bflo(q0) - bflo(r0)) * n0; ay += (bfhi(q0) - bfhi(r0)) * n0;
    }
    float v0 = tanhf(ax * (1.f / 3.f) + b[c]);
    float v1 = tanhf(ay * (1.f / 3.f) + b[c + 1]);
    if (mode == 0) {
        v0 = fmaxf(v0, 0.f); v1 = fmaxf(v1, 0.f);
        Sb[(size_t)v * 64 + lane] = packbf2(v0, v1);
    } else {
        int g = batch[v];
        atomicAdd(pool + g * H + c,     v0);
        atomicAdd(pool + g * H + c + 1, v1);
    }
}

// ---------------- final: out[g] = [mean, rel_emb] @ lin_w + lin_b ----------------
__global__ void final_kernel(const float* __restrict__ pool, const float* __restrict__ cnt,
                             const float* __restrict__ rel_table, const int* __restrict__ rel_labels,
                             const float* __restrict__ lin_w, const float* __restrict__ lin_b,
                             float* __restrict__ out) {
    int g = blockIdx.x;
    int lane = threadIdx.x;   // 64
    float inv = 1.f / fmaxf(cnt[g], 1.f);
    const float* rrow = rel_table + (size_t)rel_labels[g] * H;
    float p0 = 0.f, p1 = 0.f;
    for (int c = lane; c < H; c += 64) {
        float m = pool[g * H + c] * inv;
        p0 += m * lin_w[c * 2 + 0];
        p1 += m * lin_w[c * 2 + 1];
        float rv = rrow[c];
        p0 += rv * lin_w[(H + c) * 2 + 0];
        p1 += rv * lin_w[(H + c) * 2 + 1];
    }
    for (int off = 32; off; off >>= 1) {
        p0 += __shfl_down(p0, off);
        p1 += __shfl_down(p1, off);
    }
    if (lane == 0) {
        out[g * 2 + 0] = p0 + lin_b[0];
        out[g * 2 + 1] = p1 + lin_b[1];
    }
}

extern "C" void kernel_launch(void* const* d_in, const int* in_sizes, int n_in,
                              void* d_out, int out_size, void* d_ws, size_t ws_size,
                              hipStream_t stream) {
    const float* x          = (const float*)d_in[0];
    const int*   ei         = (const int*)  d_in[1];
    const int*   etype      = (const int*)  d_in[2];
    const int*   batch      = (const int*)  d_in[3];
    const int*   rel_labels = (const int*)  d_in[4];
    const float* rel_table  = (const float*)d_in[6];
    const float* rge        = (const float*)d_in[7];
    const float* lin_w      = (const float*)d_in[26];
    const float* lin_b      = (const float*)d_in[27];
    float* out = (float*)d_out;

    // ---- workspace layout (regions padded to 16 B) ----
    float* ws       = (float*)d_ws;
    float* dinv_in  = ws;                    // N
    float* dinv_out = dinv_in + N_NODES;     // N
    float* pool     = dinv_out + N_NODES;    // NG*H
    float* cnt      = pool + NG * H;         // NG
    float* relA     = cnt + NG;              // 201*H
    float* rbuf     = relA + RELROWS * H;    // 200*H
    float* lwl      = rbuf + 200 * H;        // 3*H
    int*   rowptr   = (int*)(lwl + 3 * H);   // N+1 (pad to N+4)
    int*   rfill    = rowptr + N_NODES + 4;  // N
    int*   cnt_dst  = rfill + N_NODES;       // N
    int*   excl     = cnt_dst + N_NODES;     // N
    int*   bsum     = excl + N_NODES;        // SCAN_NB (pad 100)
    int*   boff     = bsum + 100;            // SCAN_NB (pad 100)
    int2*  csr_mn   = (int2*)(boff + 100);   // E int2
    unsigned* QRh   = (unsigned*)(csr_mn + N_EDGES);   // NH uints (Q rows, then R rows)
    unsigned* Sb    = QRh + (size_t)NH;                // NH/2 uints (N x 128 bf16)
    unsigned* RWh   = Sb + (size_t)NH / 2;             // 3*400*64 uints
    unsigned short* Bpack = (unsigned short*)(RWh + 3 * 400 * 64);  // 9*16384 bf16

    hipMemsetAsync(dinv_in, 0, (size_t)(2 * N_NODES + NG * H + NG) * sizeof(float), stream);
    hipMemsetAsync(cnt_dst, 0, (size_t)N_NODES * sizeof(int), stream);

    deg_hist_kernel<<<(N_EDGES + 255) / 256, 256, 0, stream>>>(ei, dinv_in, dinv_out, cnt_dst);
    dinv_kernel    <<<(N_NODES + 255) / 256, 256, 0, stream>>>(dinv_in, dinv_out);
    scan1_kernel   <<<SCAN_NB, 1024, 0, stream>>>(cnt_dst, excl, bsum);
    scan2_kernel   <<<1, 128, 0, stream>>>(bsum, boff, rowptr);
    scan3_kernel   <<<SCAN_NB, 1024, 0, stream>>>(excl, boff, rowptr, rfill);
    fill_kernel    <<<(N_EDGES + 255) / 256, 256, 0, stream>>>(ei, etype, dinv_in, dinv_out,
                                                               rfill, csr_mn);
    cnt_bs_kernel  <<<NG / 64, 64, 0, stream>>>(batch, cnt);

    // pack all 9 weight matrices into MFMA B-frag order
    WPtrs wp;
    for (int l = 0; l < 3; l++) {
        wp.p[l * 3 + 0] = (const float*)d_in[8 + 6 * l + 0];  // wIn
        wp.p[l * 3 + 1] = (const float*)d_in[8 + 6 * l + 1];  // wOut
        wp.p[l * 3 + 2] = (const float*)d_in[8 + 6 * l + 2];  // wLoop
    }
    wpack_kernel<<<dim3(8, 9), 256, 0, stream>>>(wp, Bpack);

    // rel chain up-front
    for (int l = 0; l < 3; l++) {
        const float* wIn   = (const float*)d_in[8 + 6 * l + 0];
        const float* wOut  = (const float*)d_in[8 + 6 * l + 1];
        const float* wLoop = (const float*)d_in[8 + 6 * l + 2];
        const float* wRel  = (const float*)d_in[8 + 6 * l + 3];
        const float* lrel  = (const float*)d_in[8 + 6 * l + 4];
        rel_build_kernel<<<RELROWS, H, 0, stream>>>(rge, rbuf, lrel, relA, l + 1);
        rel_mm_kernel   <<<RELROWS, H, 0, stream>>>(relA, wIn, wOut, wRel, wLoop,
                                                    (unsigned short*)(RWh + (size_t)l * 400 * 64),
                                                    rbuf, lwl + l * H);
    }

    // three conv layers
    int mm_grid = (N_NODES + MMB - 1) / MMB;
    for (int l = 0; l < 3; l++) {
        const float* bl = (const float*)d_in[8 + 6 * l + 5];
        mm_mfma_kernel<<<mm_grid, 256, 0, stream>>>(x, (const unsigned short*)Sb, (l == 0) ? 1 : 0,
                                                    Bpack + (size_t)l * 3 * 16384, lwl + l * H,
                                                    (unsigned short*)QRh, (unsigned short*)Sb);
        gather_kernel<<<N_NODES / 4, 256, 0, stream>>>(rowptr, csr_mn,
                                                       QRh, RWh + (size_t)l * 400 * 64, bl,
                                                       Sb, batch, pool, (l == 2) ? 1 : 0);
    }

    final_kernel<<<NG, 64, 0, stream>>>(pool, cnt, rel_table, rel_labels, lin_w, lin_b, out);
}

// Round 9
// 735.156 us; speedup vs baseline: 1.6902x; 1.0117x over previous
//
#include <hip/hip_runtime.h>
#include <hip/hip_bf16.h>
#include <math.h>

#define N_NODES 100000
#define N_EDGES 1000000
#define HALF_E  500000
#define H       128
#define NG      256
#define RELROWS 201
#define NH      (N_NODES * H)
#define SCAN_NB 98   // 98 * 1024 >= 100000
#define XPITCH  136  // 128 + 8 bf16 pad (breaks LDS bank aliasing)
#define MMB     64   // X rows per mm block

typedef __attribute__((ext_vector_type(8))) short bf16x8;
typedef __attribute__((ext_vector_type(4))) float f32x4;

// ---- bf16 pack/unpack helpers (RNE) ----
__device__ __forceinline__ float bflo(unsigned p) { return __uint_as_float(p << 16); }
__device__ __forceinline__ float bfhi(unsigned p) { return __uint_as_float(p & 0xffff0000u); }
__device__ __forceinline__ unsigned packbf2(float a, float b) {
    unsigned ua = __float_as_uint(a), ub = __float_as_uint(b);
    ua = (ua + 0x7fffu + ((ua >> 16) & 1u)) >> 16;
    ub = (ub + 0x7fffu + ((ub >> 16) & 1u)) >> 16;
    return ua | (ub << 16);
}
__device__ __forceinline__ unsigned short packbf1(float a) {
    unsigned ua = __float_as_uint(a);
    return (unsigned short)((ua + 0x7fffu + ((ua >> 16) & 1u)) >> 16);
}

// ---- fp8 e4m3 (OCP) helpers ----
// decode: exp/mant bit-shift + 2^120 rescale trick (handles normals AND subnormals)
__device__ __forceinline__ float fp8_to_f32(unsigned v) {
    unsigned s = (v & 0x80u) << 24;
    float m = __uint_as_float((v & 0x7fu) << 20) * 0x1p+120f;
    return __uint_as_float(__float_as_uint(m) | s);
}
__device__ __forceinline__ float f8lo(unsigned p) { return fp8_to_f32(p & 0xffu); }
__device__ __forceinline__ float f8hi(unsigned p) { return fp8_to_f32((p >> 8) & 0xffu); }

#if __has_builtin(__builtin_amdgcn_cvt_pk_fp8_f32)
__device__ __forceinline__ unsigned short packfp8_2(float a, float b) {
    int v = __builtin_amdgcn_cvt_pk_fp8_f32(a, b, 0, false);
    return (unsigned short)(v & 0xffff);
}
#else
__device__ __forceinline__ unsigned fp8_enc1(float x) {
    float ax = fabsf(x);
    ax = fminf(ax, 448.f);
    unsigned sgn = (__float_as_uint(x) >> 24) & 0x80u;
    float sc = ax * 0x1p-120f;                 // target-normal -> f32 [2^-126, ...)
    unsigned b = __float_as_uint(sc);
    if (b < 0x00080000u) return sgn;           // below half min-subnormal -> 0
    unsigned r = b + 0x7ffffu + ((b >> 20) & 1u);
    return sgn | (r >> 20);
}
__device__ __forceinline__ unsigned short packfp8_2(float a, float b) {
    return (unsigned short)(fp8_enc1(a) | (fp8_enc1(b) << 8));
}
#endif

// ---------------- degree (per-direction, over src) + dst histogram ----------------
__global__ void deg_hist_kernel(const int* __restrict__ ei, float* deg_in, float* deg_out,
                                int* __restrict__ cnt_dst) {
    int e = blockIdx.x * 256 + threadIdx.x;
    if (e >= N_EDGES) return;
    int src = ei[e];
    int dst = ei[N_EDGES + e];
    if (e < HALF_E) atomicAdd(deg_in + src, 1.0f);
    else            atomicAdd(deg_out + src, 1.0f);
    atomicAdd(cnt_dst + dst, 1);
}

__global__ void dinv_kernel(float* a, float* b) {
    int i = blockIdx.x * 256 + threadIdx.x;
    if (i >= N_NODES) return;
    float d = a[i]; a[i] = d > 0.f ? rsqrtf(d) : 0.f;
    d = b[i];       b[i] = d > 0.f ? rsqrtf(d) : 0.f;
}

// ---------------- 3-phase exclusive scan over cnt_dst ----------------
__global__ __launch_bounds__(1024) void scan1_kernel(const int* __restrict__ cnt,
                                                     int* __restrict__ excl,
                                                     int* __restrict__ bsum) {
    __shared__ int ps[1024];
    int t = threadIdx.x;
    int i = blockIdx.x * 1024 + t;
    int v = (i < N_NODES) ? cnt[i] : 0;
    ps[t] = v;
    __syncthreads();
    for (int off = 1; off < 1024; off <<= 1) {
        int u = (t >= off) ? ps[t - off] : 0;
        __syncthreads();
        ps[t] += u;
        __syncthreads();
    }
    if (i < N_NODES) excl[i] = ps[t] - v;
    if (t == 1023) bsum[blockIdx.x] = ps[t];
}

__global__ __launch_bounds__(128) void scan2_kernel(const int* __restrict__ bsum,
                                                    int* __restrict__ boff,
                                                    int* __restrict__ rowptr) {
    __shared__ int ps[128];
    int t = threadIdx.x;
    int v = (t < SCAN_NB) ? bsum[t] : 0;
    ps[t] = v;
    __syncthreads();
    for (int off = 1; off < 128; off <<= 1) {
        int u = (t >= off) ? ps[t - off] : 0;
        __syncthreads();
        ps[t] += u;
        __syncthreads();
    }
    if (t < SCAN_NB) boff[t] = ps[t] - v;
    if (t == 127) rowptr[N_NODES] = ps[t];
}

__global__ __launch_bounds__(1024) void scan3_kernel(const int* __restrict__ excl,
                                                     const int* __restrict__ boff,
                                                     int* __restrict__ rowptr,
                                                     int* __restrict__ rfill) {
    int t = threadIdx.x;
    int i = blockIdx.x * 1024 + t;
    if (i >= N_NODES) return;
    int r = excl[i] + boff[blockIdx.x];
    rowptr[i] = r;
    rfill[i] = r;
}

// ---------------- fill CSR: mn = { (src + dir*N) | ((typ + dir*200) << 18), bits(norm) } ----------------
__global__ void fill_kernel(const int* __restrict__ ei, const int* __restrict__ etype,
                            const float* __restrict__ dinv_in, const float* __restrict__ dinv_out,
                            int* __restrict__ rfill, int2* __restrict__ csr_mn) {
    int e = blockIdx.x * 256 + threadIdx.x;
    if (e >= N_EDGES) return;
    int s = ei[e], d = ei[N_EDGES + e];
    int t = etype[e];
    bool isin = (e < HALF_E);
    const float* dv = isin ? dinv_in : dinv_out;
    float nv = dv[s] * dv[d];
    int j = atomicAdd(rfill + d, 1);
    int src2 = s + (isin ? 0 : N_NODES);
    int typ2 = t + (isin ? 0 : 200);
    csr_mn[j] = make_int2(src2 | (typ2 << 18), __float_as_int(nv));
}

// ---------------- per-graph node counts via binary search (batch is sorted) ----------------
__global__ void cnt_bs_kernel(const int* __restrict__ batch, float* __restrict__ cnt) {
    int g = blockIdx.x * 64 + threadIdx.x;
    if (g >= NG) return;
    int lo = 0, hi = N_NODES;
    while (lo < hi) { int mid = (lo + hi) >> 1; if (batch[mid] < g) lo = mid + 1; else hi = mid; }
    int start = lo;
    lo = 0; hi = N_NODES;
    while (lo < hi) { int mid = (lo + hi) >> 1; if (batch[mid] < g + 1) lo = mid + 1; else hi = mid; }
    cnt[g] = (float)(lo - start);
}

// ---------------- rel chain (tiny) ----------------
__global__ void rel_build_kernel(const float* __restrict__ rge, const float* __restrict__ rbuf,
                                 const float* __restrict__ loop_rel, float* __restrict__ relA, int layer) {
    int i = blockIdx.x;      // 0..200
    int j = threadIdx.x;     // 0..127
    float v;
    if (i == 200)          v = loop_rel[j];
    else if (layer == 1)   v = (i < 100) ? rge[i * H + j] : -rge[(i - 100) * H + j];
    else                   v = rbuf[i * H + j];
    relA[i * H + j] = v;
}

// RWf8 layout per layer (fp8): rows 0..199 = rel@w_in, rows 200..399 = rel@w_out (64 ushorts/row)
__global__ void rel_mm_kernel(const float* __restrict__ relA,
                              const float* __restrict__ wIn, const float* __restrict__ wOut,
                              const float* __restrict__ wRel, const float* __restrict__ wLoop,
                              unsigned short* __restrict__ RWf8, float* __restrict__ rbuf,
                              float* __restrict__ lwl) {
    __shared__ float a[H];
    int i = blockIdx.x, j = threadIdx.x;
    a[j] = relA[i * H + j];
    __syncthreads();
    float s_in = 0.f, s_out = 0.f, s_rel = 0.f, s_loop = 0.f;
    for (int k = 0; k < H; k++) {
        float av = a[k];
        s_in  += av * wIn [k * H + j];
        s_out += av * wOut[k * H + j];
        s_rel += av * wRel[k * H + j];
        s_loop += av * wLoop[k * H + j];
    }
    // pair adjacent columns (j even gets j, j^1) for fp8 ushort store
    float in_n  = __shfl_xor(s_in, 1);
    float out_n = __shfl_xor(s_out, 1);
    if (i < 200) {
        if ((j & 1) == 0) {
            RWf8[i * 64 + (j >> 1)]         = packfp8_2(s_in, in_n);
            RWf8[(200 + i) * 64 + (j >> 1)] = packfp8_2(s_out, out_n);
        }
        rbuf[i * H + j] = s_rel;
    }
    if (i == 200) lwl[j] = s_loop;
}

// ---------------- weight pre-pack into MFMA B-fragment order (bf16) ----------------
struct WPtrs { const float* p[9]; };
__global__ __launch_bounds__(256) void wpack_kernel(WPtrs wp, unsigned short* __restrict__ Bp) {
    int iw = blockIdx.y;  // l*3 + w
    const float* W = wp.p[iw];
    unsigned short* out = Bp + (size_t)iw * 16384;
    int t = blockIdx.x * 256 + threadIdx.x;   // 0..2047
    int nt = t >> 8, kk = (t >> 6) & 3, lane = t & 63;
    int n = nt * 16 + (lane & 15);
    int k0 = kk * 32 + (lane >> 4) * 8;
    unsigned p[4];
    for (int j = 0; j < 4; j++)
        p[j] = packbf2(W[(k0 + 2 * j) * H + n], W[(k0 + 2 * j + 1) * H + n]);
    *(uint4*)(out + ((size_t)(nt * 4 + kk) * 64 + lane) * 8) = make_uint4(p[0], p[1], p[2], p[3]);
}

// ---------------- MFMA node matmuls: Qf8=X@wIn, Rf8=X@wOut (fp8), Sb=X@wLoop - lwl (bf16) ----------------
__global__ __launch_bounds__(256) void mm_mfma_kernel(const float* __restrict__ Xf,
                                                      const unsigned short* __restrict__ Xh,
                                                      int xf32,
                                                      const unsigned short* __restrict__ Bpack,
                                                      const float* __restrict__ lwl,
                                                      unsigned short* __restrict__ QRf8,
                                                      unsigned short* __restrict__ Sb) {
    __shared__ unsigned short xt[MMB * XPITCH];
    int tid = threadIdx.x;
    int row0 = blockIdx.x * MMB;
    int nrows = min(MMB, N_NODES - row0);
    if (xf32) {
        for (int t = 0; t < 8; t++) {
            int idx = tid + t * 256;                 // 2048 float4s
            int r = idx >> 5, c4 = (idx & 31) * 4;
            if (r < nrows) {
                float4 v = *(const float4*)(Xf + (size_t)(row0 + r) * H + c4);
                *(uint2*)(xt + r * XPITCH + c4) = make_uint2(packbf2(v.x, v.y), packbf2(v.z, v.w));
            }
        }
    } else {
        for (int t = 0; t < 4; t++) {
            int idx = tid + t * 256;                 // 1024 uint4s (8 bf16 each)
            int r = idx >> 4, c8 = (idx & 15) * 8;
            if (r < nrows)
                *(uint4*)(xt + r * XPITCH + c8) = *(const uint4*)(Xh + (size_t)(row0 + r) * H + c8);
        }
    }
    __syncthreads();

    int wave = tid >> 6, lane = tid & 63;
    int m0w = wave * 16;
    int q = lane >> 4, ml = lane & 15;
    bf16x8 afrag[4];
    for (int kk = 0; kk < 4; kk++)
        afrag[kk] = *(const bf16x8*)(xt + (m0w + ml) * XPITCH + kk * 32 + q * 8);
    int grow_base = row0 + m0w + q * 4;
    for (int w = 0; w < 3; w++) {
        for (int nt = 0; nt < 8; nt++) {
            const unsigned short* bp = Bpack + (((size_t)(w * 8 + nt) * 4) * 64 + lane) * 8;
            f32x4 acc = {0.f, 0.f, 0.f, 0.f};
            for (int kk = 0; kk < 4; kk++) {
                bf16x8 bfrag = *(const bf16x8*)(bp + (size_t)kk * 512);
                acc = __builtin_amdgcn_mfma_f32_16x16x32_bf16(afrag[kk], bfrag, acc, 0, 0, 0);
            }
            int col = nt * 16 + ml;
            if (w < 2) {
                size_t rbase = (w == 0) ? 0 : (size_t)N_NODES;
                for (int reg = 0; reg < 4; reg++) {
                    float v = acc[reg];
                    float vn = __shfl_xor(v, 1);     // neighbor column's value
                    int grow = grow_base + reg;
                    if (((lane & 1) == 0) && grow < N_NODES)
                        QRf8[(rbase + grow) * 64 + (col >> 1)] = packfp8_2(v, vn);
                }
            } else {
                float sub = lwl[col];
                for (int reg = 0; reg < 4; reg++) {
                    int grow = grow_base + reg;
                    if (grow < N_NODES)
                        Sb[(size_t)grow * H + col] = packbf1(acc[reg] - sub);
                }
            }
        }
    }
}

// ---------------- gather + combine: one wave per dst node, fp8 ushort loads, 8x unroll ----------------
__global__ __launch_bounds__(256) void gather_kernel(const int* __restrict__ rowptr,
                                                     const int2* __restrict__ csr_mn,
                                                     const unsigned short* __restrict__ QRf8,
                                                     const unsigned short* __restrict__ RWf8,
                                                     const float* __restrict__ b,
                                                     unsigned* __restrict__ Sb,
                                                     const int* __restrict__ batch,
                                                     float* __restrict__ pool, int mode) {
    int v = blockIdx.x * 4 + (threadIdx.x >> 6);
    if (v >= N_NODES) return;
    int lane = threadIdx.x & 63;
    int c = lane * 2;
    int jb = rowptr[v], je = rowptr[v + 1];
    unsigned sv = Sb[(size_t)v * 64 + lane];
    float ax = bflo(sv), ay = bfhi(sv);   // loop term (bf16)
    int j = jb;
    for (; j + 7 < je; j += 8) {
        int2 mn[8];
        #pragma unroll
        for (int k = 0; k < 8; k++) mn[k] = csr_mn[j + k];
        unsigned short q[8], r[8];
        #pragma unroll
        for (int k = 0; k < 8; k++) {
            q[k] = QRf8[(size_t)(mn[k].x & 0x3FFFF) * 64 + lane];
            r[k] = RWf8[(size_t)((unsigned)mn[k].x >> 18) * 64 + lane];
        }
        #pragma unroll
        for (int k = 0; k < 8; k++) {
            float n = __int_as_float(mn[k].y);
            ax += (f8lo(q[k]) - f8lo(r[k])) * n;
            ay += (f8hi(q[k]) - f8hi(r[k])) * n;
        }
    }
    for (; j + 1 < je; j += 2) {
        int2 mn0 = csr_mn[j], mn1 = csr_mn[j + 1];
        unsigned short q0 = QRf8[(size_t)(mn0.x & 0x3FFFF) * 64 + lane];
        unsigned short r0 = RWf8[(size_t)((unsigned)mn0.x >> 18) * 64 + lane];
        unsigned short q1 = QRf8[(size_t)(mn1.x & 0x3FFFF) * 64 + lane];
        unsigned short r1 = RWf8[(size_t)((unsigned)mn1.x >> 18) * 64 + lane];
        float n0 = __int_as_float(mn0.y), n1 = __int_as_float(mn1.y);
        ax += (f8lo(q0) - f8lo(r0)) * n0; ay += (f8hi(q0) - f8hi(r0)) * n0;
        ax += (f8lo(q1) - f8lo(r1)) * n1; ay += (f8hi(q1) - f8hi(r1)) * n1;
    }
    if (j < je) {
        int2 mn0 = csr_mn[j];
        float n0 = __int_as_float(mn0.y);
        unsigned short q0 = QRf8[(size_t)(mn0.x & 0x3FFFF) * 64 + lane];
        unsigned short r0 = RWf8[(size_t)((unsigned)mn0.x >> 18) * 64 + lane];
        ax += (f8lo(q0) - f8lo(r0)) * n0; ay += (f8hi(q0) - f8hi(r0)) * n0;
    }
    float v0 = tanhf(ax * (1.f / 3.f) + b[c]);
    float v1 = tanhf(ay * (1.f / 3.f) + b[c + 1]);
    if (mode == 0) {
        v0 = fmaxf(v0, 0.f); v1 = fmaxf(v1, 0.f);
        Sb[(size_t)v * 64 + lane] = packbf2(v0, v1);
    } else {
        int g = batch[v];
        atomicAdd(pool + g * H + c,     v0);
        atomicAdd(pool + g * H + c + 1, v1);
    }
}

// ---------------- final: out[g] = [mean, rel_emb] @ lin_w + lin_b ----------------
__global__ void final_kernel(const float* __restrict__ pool, const float* __restrict__ cnt,
                             const float* __restrict__ rel_table, const int* __restrict__ rel_labels,
                             const float* __restrict__ lin_w, const float* __restrict__ lin_b,
                             float* __restrict__ out) {
    int g = blockIdx.x;
    int lane = threadIdx.x;   // 64
    float inv = 1.f / fmaxf(cnt[g], 1.f);
    const float* rrow = rel_table + (size_t)rel_labels[g] * H;
    float p0 = 0.f, p1 = 0.f;
    for (int c = lane; c < H; c += 64) {
        float m = pool[g * H + c] * inv;
        p0 += m * lin_w[c * 2 + 0];
        p1 += m * lin_w[c * 2 + 1];
        float rv = rrow[c];
        p0 += rv * lin_w[(H + c) * 2 + 0];
        p1 += rv * lin_w[(H + c) * 2 + 1];
    }
    for (int off = 32; off; off >>= 1) {
        p0 += __shfl_down(p0, off);
        p1 += __shfl_down(p1, off);
    }
    if (lane == 0) {
        out[g * 2 + 0] = p0 + lin_b[0];
        out[g * 2 + 1] = p1 + lin_b[1];
    }
}

extern "C" void kernel_launch(void* const* d_in, const int* in_sizes, int n_in,
                              void* d_out, int out_size, void* d_ws, size_t ws_size,
                              hipStream_t stream) {
    const float* x          = (const float*)d_in[0];
    const int*   ei         = (const int*)  d_in[1];
    const int*   etype      = (const int*)  d_in[2];
    const int*   batch      = (const int*)  d_in[3];
    const int*   rel_labels = (const int*)  d_in[4];
    const float* rel_table  = (const float*)d_in[6];
    const float* rge        = (const float*)d_in[7];
    const float* lin_w      = (const float*)d_in[26];
    const float* lin_b      = (const float*)d_in[27];
    float* out = (float*)d_out;

    // ---- workspace layout (regions padded to 16 B) ----
    float* ws       = (float*)d_ws;
    float* dinv_in  = ws;                    // N
    float* dinv_out = dinv_in + N_NODES;     // N
    float* pool     = dinv_out + N_NODES;    // NG*H
    float* cnt      = pool + NG * H;         // NG
    float* relA     = cnt + NG;              // 201*H
    float* rbuf     = relA + RELROWS * H;    // 200*H
    float* lwl      = rbuf + 200 * H;        // 3*H
    int*   rowptr   = (int*)(lwl + 3 * H);   // N+1 (pad to N+4)
    int*   rfill    = rowptr + N_NODES + 4;  // N
    int*   cnt_dst  = rfill + N_NODES;       // N
    int*   excl     = cnt_dst + N_NODES;     // N
    int*   bsum     = excl + N_NODES;        // SCAN_NB (pad 100)
    int*   boff     = bsum + 100;            // SCAN_NB (pad 100)
    int2*  csr_mn   = (int2*)(boff + 100);   // E int2
    unsigned short* QRf8 = (unsigned short*)(csr_mn + N_EDGES);   // 2N rows x 64 ushorts (fp8 pairs)
    unsigned* Sb    = (unsigned*)(QRf8 + (size_t)2 * N_NODES * 64);  // N x 64 uints (bf16 pairs)
    unsigned short* RWf8 = (unsigned short*)(Sb + (size_t)N_NODES * 64);  // 3 * 400 * 64 ushorts
    unsigned short* Bpack = RWf8 + (size_t)3 * 400 * 64;  // 9*16384 bf16

    hipMemsetAsync(dinv_in, 0, (size_t)(2 * N_NODES + NG * H + NG) * sizeof(float), stream);
    hipMemsetAsync(cnt_dst, 0, (size_t)N_NODES * sizeof(int), stream);

    deg_hist_kernel<<<(N_EDGES + 255) / 256, 256, 0, stream>>>(ei, dinv_in, dinv_out, cnt_dst);
    dinv_kernel    <<<(N_NODES + 255) / 256, 256, 0, stream>>>(dinv_in, dinv_out);
    scan1_kernel   <<<SCAN_NB, 1024, 0, stream>>>(cnt_dst, excl, bsum);
    scan2_kernel   <<<1, 128, 0, stream>>>(bsum, boff, rowptr);
    scan3_kernel   <<<SCAN_NB, 1024, 0, stream>>>(excl, boff, rowptr, rfill);
    fill_kernel    <<<(N_EDGES + 255) / 256, 256, 0, stream>>>(ei, etype, dinv_in, dinv_out,
                                                               rfill, csr_mn);
    cnt_bs_kernel  <<<NG / 64, 64, 0, stream>>>(batch, cnt);

    // pack all 9 weight matrices into MFMA B-frag order
    WPtrs wp;
    for (int l = 0; l < 3; l++) {
        wp.p[l * 3 + 0] = (const float*)d_in[8 + 6 * l + 0];  // wIn
        wp.p[l * 3 + 1] = (const float*)d_in[8 + 6 * l + 1];  // wOut
        wp.p[l * 3 + 2] = (const float*)d_in[8 + 6 * l + 2];  // wLoop
    }
    wpack_kernel<<<dim3(8, 9), 256, 0, stream>>>(wp, Bpack);

    // rel chain up-front
    for (int l = 0; l < 3; l++) {
        const float* wIn   = (const float*)d_in[8 + 6 * l + 0];
        const float* wOut  = (const float*)d_in[8 + 6 * l + 1];
        const float* wLoop = (const float*)d_in[8 + 6 * l + 2];
        const float* wRel  = (const float*)d_in[8 + 6 * l + 3];
        const float* lrel  = (const float*)d_in[8 + 6 * l + 4];
        rel_build_kernel<<<RELROWS, H, 0, stream>>>(rge, rbuf, lrel, relA, l + 1);
        rel_mm_kernel   <<<RELROWS, H, 0, stream>>>(relA, wIn, wOut, wRel, wLoop,
                                                    RWf8 + (size_t)l * 400 * 64,
                                                    rbuf, lwl + l * H);
    }

    // three conv layers
    int mm_grid = (N_NODES + MMB - 1) / MMB;
    for (int l = 0; l < 3; l++) {
        const float* bl = (const float*)d_in[8 + 6 * l + 5];
        mm_mfma_kernel<<<mm_grid, 256, 0, stream>>>(x, (const unsigned short*)Sb, (l == 0) ? 1 : 0,
                                                    Bpack + (size_t)l * 3 * 16384, lwl + l * H,
                                                    QRf8, (unsigned short*)Sb);
        gather_kernel<<<N_NODES / 4, 256, 0, stream>>>(rowptr, csr_mn,
                                                       QRf8, RWf8 + (size_t)l * 400 * 64, bl,
                                                       Sb, batch, pool, (l == 2) ? 1 : 0);
    }

    final_kernel<<<NG, 64, 0, stream>>>(pool, cnt, rel_table, rel_labels, lin_w, lin_b, out);
}

// Round 10
// 720.605 us; speedup vs baseline: 1.7243x; 1.0202x over previous
//
#include <hip/hip_runtime.h>
#include <hip/hip_bf16.h>
#include <math.h>

#define N_NODES 100000
#define N_EDGES 1000000
#define HALF_E  500000
#define H       128
#define NG      256
#define RELROWS 201
#define NH      (N_NODES * H)
#define SCAN_NB 98   // 98 * 1024 >= 100000
#define XPITCH  136  // 128 + 8 bf16 pad (breaks LDS bank aliasing)
#define MMB     64   // X rows per mm block

typedef __attribute__((ext_vector_type(8))) short bf16x8;
typedef __attribute__((ext_vector_type(4))) float f32x4;
typedef __attribute__((ext_vector_type(2))) float f32x2;

// ---- bf16 pack/unpack helpers (RNE) ----
__device__ __forceinline__ float bflo(unsigned p) { return __uint_as_float(p << 16); }
__device__ __forceinline__ float bfhi(unsigned p) { return __uint_as_float(p & 0xffff0000u); }
__device__ __forceinline__ unsigned packbf2(float a, float b) {
    unsigned ua = __float_as_uint(a), ub = __float_as_uint(b);
    ua = (ua + 0x7fffu + ((ua >> 16) & 1u)) >> 16;
    ub = (ub + 0x7fffu + ((ub >> 16) & 1u)) >> 16;
    return ua | (ub << 16);
}
__device__ __forceinline__ unsigned short packbf1(float a) {
    unsigned ua = __float_as_uint(a);
    return (unsigned short)((ua + 0x7fffu + ((ua >> 16) & 1u)) >> 16);
}

// ---- fp8 e4m3 (OCP) helpers ----
__device__ __forceinline__ float fp8_to_f32(unsigned v) {
    unsigned s = (v & 0x80u) << 24;
    float m = __uint_as_float((v & 0x7fu) << 20) * 0x1p+120f;
    return __uint_as_float(__float_as_uint(m) | s);
}

#if __has_builtin(__builtin_amdgcn_cvt_pk_f32_fp8)
__device__ __forceinline__ f32x2 f8pair(unsigned short p) {
    return __builtin_amdgcn_cvt_pk_f32_fp8((int)(unsigned)p, false);
}
#else
__device__ __forceinline__ f32x2 f8pair(unsigned short p) {
    f32x2 r;
    r.x = fp8_to_f32(p & 0xffu);
    r.y = fp8_to_f32((p >> 8) & 0xffu);
    return r;
}
#endif

#if __has_builtin(__builtin_amdgcn_cvt_pk_fp8_f32)
__device__ __forceinline__ unsigned short packfp8_2(float a, float b) {
    int v = __builtin_amdgcn_cvt_pk_fp8_f32(a, b, 0, false);
    return (unsigned short)(v & 0xffff);
}
#else
__device__ __forceinline__ unsigned fp8_enc1(float x) {
    float ax = fabsf(x);
    ax = fminf(ax, 448.f);
    unsigned sgn = (__float_as_uint(x) >> 24) & 0x80u;
    float sc = ax * 0x1p-120f;
    unsigned b = __float_as_uint(sc);
    if (b < 0x00080000u) return sgn;
    unsigned r = b + 0x7ffffu + ((b >> 20) & 1u);
    return sgn | (r >> 20);
}
__device__ __forceinline__ unsigned short packfp8_2(float a, float b) {
    return (unsigned short)(fp8_enc1(a) | (fp8_enc1(b) << 8));
}
#endif

// ---------------- degree (per-direction, over src) + dst histogram ----------------
__global__ void deg_hist_kernel(const int* __restrict__ ei, float* deg_in, float* deg_out,
                                int* __restrict__ cnt_dst) {
    int e = blockIdx.x * 256 + threadIdx.x;
    if (e >= N_EDGES) return;
    int src = ei[e];
    int dst = ei[N_EDGES + e];
    if (e < HALF_E) atomicAdd(deg_in + src, 1.0f);
    else            atomicAdd(deg_out + src, 1.0f);
    atomicAdd(cnt_dst + dst, 1);
}

__global__ void dinv_kernel(float* a, float* b) {
    int i = blockIdx.x * 256 + threadIdx.x;
    if (i >= N_NODES) return;
    float d = a[i]; a[i] = d > 0.f ? rsqrtf(d) : 0.f;
    d = b[i];       b[i] = d > 0.f ? rsqrtf(d) : 0.f;
}

// ---------------- 3-phase exclusive scan over cnt_dst ----------------
__global__ __launch_bounds__(1024) void scan1_kernel(const int* __restrict__ cnt,
                                                     int* __restrict__ excl,
                                                     int* __restrict__ bsum) {
    __shared__ int ps[1024];
    int t = threadIdx.x;
    int i = blockIdx.x * 1024 + t;
    int v = (i < N_NODES) ? cnt[i] : 0;
    ps[t] = v;
    __syncthreads();
    for (int off = 1; off < 1024; off <<= 1) {
        int u = (t >= off) ? ps[t - off] : 0;
        __syncthreads();
        ps[t] += u;
        __syncthreads();
    }
    if (i < N_NODES) excl[i] = ps[t] - v;
    if (t == 1023) bsum[blockIdx.x] = ps[t];
}

__global__ __launch_bounds__(128) void scan2_kernel(const int* __restrict__ bsum,
                                                    int* __restrict__ boff,
                                                    int* __restrict__ rowptr) {
    __shared__ int ps[128];
    int t = threadIdx.x;
    int v = (t < SCAN_NB) ? bsum[t] : 0;
    ps[t] = v;
    __syncthreads();
    for (int off = 1; off < 128; off <<= 1) {
        int u = (t >= off) ? ps[t - off] : 0;
        __syncthreads();
        ps[t] += u;
        __syncthreads();
    }
    if (t < SCAN_NB) boff[t] = ps[t] - v;
    if (t == 127) rowptr[N_NODES] = ps[t];
}

__global__ __launch_bounds__(1024) void scan3_kernel(const int* __restrict__ excl,
                                                     const int* __restrict__ boff,
                                                     int* __restrict__ rowptr,
                                                     int* __restrict__ rfill) {
    int t = threadIdx.x;
    int i = blockIdx.x * 1024 + t;
    if (i >= N_NODES) return;
    int r = excl[i] + boff[blockIdx.x];
    rowptr[i] = r;
    rfill[i] = r;
}

// ---------------- fill CSR: mn = { (src + dir*N) | ((typ + dir*200) << 18), bits(norm) } ----------------
__global__ void fill_kernel(const int* __restrict__ ei, const int* __restrict__ etype,
                            const float* __restrict__ dinv_in, const float* __restrict__ dinv_out,
                            int* __restrict__ rfill, int2* __restrict__ csr_mn) {
    int e = blockIdx.x * 256 + threadIdx.x;
    if (e >= N_EDGES) return;
    int s = ei[e], d = ei[N_EDGES + e];
    int t = etype[e];
    bool isin = (e < HALF_E);
    const float* dv = isin ? dinv_in : dinv_out;
    float nv = dv[s] * dv[d];
    int j = atomicAdd(rfill + d, 1);
    int src2 = s + (isin ? 0 : N_NODES);
    int typ2 = t + (isin ? 0 : 200);
    csr_mn[j] = make_int2(src2 | (typ2 << 18), __float_as_int(nv));
}

// ---------------- per-graph node counts via binary search (batch is sorted) ----------------
__global__ void cnt_bs_kernel(const int* __restrict__ batch, float* __restrict__ cnt) {
    int g = blockIdx.x * 64 + threadIdx.x;
    if (g >= NG) return;
    int lo = 0, hi = N_NODES;
    while (lo < hi) { int mid = (lo + hi) >> 1; if (batch[mid] < g) lo = mid + 1; else hi = mid; }
    int start = lo;
    lo = 0; hi = N_NODES;
    while (lo < hi) { int mid = (lo + hi) >> 1; if (batch[mid] < g + 1) lo = mid + 1; else hi = mid; }
    cnt[g] = (float)(lo - start);
}

// ---------------- rel chain (tiny) ----------------
__global__ void rel_build_kernel(const float* __restrict__ rge, const float* __restrict__ rbuf,
                                 const float* __restrict__ loop_rel, float* __restrict__ relA, int layer) {
    int i = blockIdx.x;      // 0..200
    int j = threadIdx.x;     // 0..127
    float v;
    if (i == 200)          v = loop_rel[j];
    else if (layer == 1)   v = (i < 100) ? rge[i * H + j] : -rge[(i - 100) * H + j];
    else                   v = rbuf[i * H + j];
    relA[i * H + j] = v;
}

// RWf8 layout per layer (fp8): rows 0..199 = rel@w_in, rows 200..399 = rel@w_out (64 ushorts/row)
__global__ void rel_mm_kernel(const float* __restrict__ relA,
                              const float* __restrict__ wIn, const float* __restrict__ wOut,
                              const float* __restrict__ wRel, const float* __restrict__ wLoop,
                              unsigned short* __restrict__ RWf8, float* __restrict__ rbuf,
                              float* __restrict__ lwl) {
    __shared__ float a[H];
    int i = blockIdx.x, j = threadIdx.x;
    a[j] = relA[i * H + j];
    __syncthreads();
    float s_in = 0.f, s_out = 0.f, s_rel = 0.f, s_loop = 0.f;
    for (int k = 0; k < H; k++) {
        float av = a[k];
        s_in  += av * wIn [k * H + j];
        s_out += av * wOut[k * H + j];
        s_rel += av * wRel[k * H + j];
        s_loop += av * wLoop[k * H + j];
    }
    float in_n  = __shfl_xor(s_in, 1);
    float out_n = __shfl_xor(s_out, 1);
    if (i < 200) {
        if ((j & 1) == 0) {
            RWf8[i * 64 + (j >> 1)]         = packfp8_2(s_in, in_n);
            RWf8[(200 + i) * 64 + (j >> 1)] = packfp8_2(s_out, out_n);
        }
        rbuf[i * H + j] = s_rel;
    }
    if (i == 200) lwl[j] = s_loop;
}

// ---------------- weight pre-pack into MFMA B-fragment order (bf16) ----------------
struct WPtrs { const float* p[9]; };
__global__ __launch_bounds__(256) void wpack_kernel(WPtrs wp, unsigned short* __restrict__ Bp) {
    int iw = blockIdx.y;  // l*3 + w
    const float* W = wp.p[iw];
    unsigned short* out = Bp + (size_t)iw * 16384;
    int t = blockIdx.x * 256 + threadIdx.x;   // 0..2047
    int nt = t >> 8, kk = (t >> 6) & 3, lane = t & 63;
    int n = nt * 16 + (lane & 15);
    int k0 = kk * 32 + (lane >> 4) * 8;
    unsigned p[4];
    for (int j = 0; j < 4; j++)
        p[j] = packbf2(W[(k0 + 2 * j) * H + n], W[(k0 + 2 * j + 1) * H + n]);
    *(uint4*)(out + ((size_t)(nt * 4 + kk) * 64 + lane) * 8) = make_uint4(p[0], p[1], p[2], p[3]);
}

// ---------------- MFMA node matmuls: Qf8=X@wIn, Rf8=X@wOut (fp8), Sb=X@wLoop - lwl (bf16) ----------------
__global__ __launch_bounds__(256) void mm_mfma_kernel(const float* __restrict__ Xf,
                                                      const unsigned short* __restrict__ Xh,
                                                      int xf32,
                                                      const unsigned short* __restrict__ Bpack,
                                                      const float* __restrict__ lwl,
                                                      unsigned short* __restrict__ QRf8,
                                                      unsigned short* __restrict__ Sb) {
    __shared__ unsigned short xt[MMB * XPITCH];
    int tid = threadIdx.x;
    int row0 = blockIdx.x * MMB;
    int nrows = min(MMB, N_NODES - row0);
    if (xf32) {
        for (int t = 0; t < 8; t++) {
            int idx = tid + t * 256;                 // 2048 float4s
            int r = idx >> 5, c4 = (idx & 31) * 4;
            if (r < nrows) {
                float4 v = *(const float4*)(Xf + (size_t)(row0 + r) * H + c4);
                *(uint2*)(xt + r * XPITCH + c4) = make_uint2(packbf2(v.x, v.y), packbf2(v.z, v.w));
            }
        }
    } else {
        for (int t = 0; t < 4; t++) {
            int idx = tid + t * 256;                 // 1024 uint4s (8 bf16 each)
            int r = idx >> 4, c8 = (idx & 15) * 8;
            if (r < nrows)
                *(uint4*)(xt + r * XPITCH + c8) = *(const uint4*)(Xh + (size_t)(row0 + r) * H + c8);
        }
    }
    __syncthreads();

    int wave = tid >> 6, lane = tid & 63;
    int m0w = wave * 16;
    int q = lane >> 4, ml = lane & 15;
    bf16x8 afrag[4];
    for (int kk = 0; kk < 4; kk++)
        afrag[kk] = *(const bf16x8*)(xt + (m0w + ml) * XPITCH + kk * 32 + q * 8);
    int grow_base = row0 + m0w + q * 4;
    for (int w = 0; w < 3; w++) {
        for (int nt = 0; nt < 8; nt++) {
            const unsigned short* bp = Bpack + (((size_t)(w * 8 + nt) * 4) * 64 + lane) * 8;
            f32x4 acc = {0.f, 0.f, 0.f, 0.f};
            for (int kk = 0; kk < 4; kk++) {
                bf16x8 bfrag = *(const bf16x8*)(bp + (size_t)kk * 512);
                acc = __builtin_amdgcn_mfma_f32_16x16x32_bf16(afrag[kk], bfrag, acc, 0, 0, 0);
            }
            int col = nt * 16 + ml;
            if (w < 2) {
                size_t rbase = (w == 0) ? 0 : (size_t)N_NODES;
                for (int reg = 0; reg < 4; reg++) {
                    float v = acc[reg];
                    float vn = __shfl_xor(v, 1);     // neighbor column's value
                    int grow = grow_base + reg;
                    if (((lane & 1) == 0) && grow < N_NODES)
                        QRf8[(rbase + grow) * 64 + (col >> 1)] = packfp8_2(v, vn);
                }
            } else {
                float sub = lwl[col];
                for (int reg = 0; reg < 4; reg++) {
                    int grow = grow_base + reg;
                    if (grow < N_NODES)
                        Sb[(size_t)grow * H + col] = packbf1(acc[reg] - sub);
                }
            }
        }
    }
}

// ---------------- gather + combine: one wave per dst node, fp8 ushort loads, hw cvt, 8x unroll ----------------
__global__ __launch_bounds__(256, 8) void gather_kernel(const int* __restrict__ rowptr,
                                                        const int2* __restrict__ csr_mn,
                                                        const unsigned short* __restrict__ QRf8,
                                                        const unsigned short* __restrict__ RWf8,
                                                        const float* __restrict__ b,
                                                        unsigned* __restrict__ Sb,
                                                        const int* __restrict__ batch,
                                                        float* __restrict__ pool, int mode) {
    int v = blockIdx.x * 4 + (threadIdx.x >> 6);
    if (v >= N_NODES) return;
    int lane = threadIdx.x & 63;
    int c = lane * 2;
    int jb = rowptr[v], je = rowptr[v + 1];
    unsigned sv = Sb[(size_t)v * 64 + lane];
    float ax = bflo(sv), ay = bfhi(sv);   // loop term (bf16)
    int j = jb;
    for (; j + 7 < je; j += 8) {
        int2 mn[8];
        #pragma unroll
        for (int k = 0; k < 8; k++) mn[k] = csr_mn[j + k];
        unsigned short q[8], r[8];
        #pragma unroll
        for (int k = 0; k < 8; k++) {
            q[k] = QRf8[(size_t)(mn[k].x & 0x3FFFF) * 64 + lane];
            r[k] = RWf8[(size_t)((unsigned)mn[k].x >> 18) * 64 + lane];
        }
        #pragma unroll
        for (int k = 0; k < 8; k++) {
            float n = __int_as_float(mn[k].y);
            f32x2 dq = f8pair(q[k]);
            f32x2 dr = f8pair(r[k]);
            ax += (dq.x - dr.x) * n;
            ay += (dq.y - dr.y) * n;
        }
    }
    for (; j + 1 < je; j += 2) {
        int2 mn0 = csr_mn[j], mn1 = csr_mn[j + 1];
        unsigned short q0 = QRf8[(size_t)(mn0.x & 0x3FFFF) * 64 + lane];
        unsigned short r0 = RWf8[(size_t)((unsigned)mn0.x >> 18) * 64 + lane];
        unsigned short q1 = QRf8[(size_t)(mn1.x & 0x3FFFF) * 64 + lane];
        unsigned short r1 = RWf8[(size_t)((unsigned)mn1.x >> 18) * 64 + lane];
        float n0 = __int_as_float(mn0.y), n1 = __int_as_float(mn1.y);
        f32x2 dq0 = f8pair(q0), dr0 = f8pair(r0);
        f32x2 dq1 = f8pair(q1), dr1 = f8pair(r1);
        ax += (dq0.x - dr0.x) * n0; ay += (dq0.y - dr0.y) * n0;
        ax += (dq1.x - dr1.x) * n1; ay += (dq1.y - dr1.y) * n1;
    }
    if (j < je) {
        int2 mn0 = csr_mn[j];
        float n0 = __int_as_float(mn0.y);
        unsigned short q0 = QRf8[(size_t)(mn0.x & 0x3FFFF) * 64 + lane];
        unsigned short r0 = RWf8[(size_t)((unsigned)mn0.x >> 18) * 64 + lane];
        f32x2 dq0 = f8pair(q0), dr0 = f8pair(r0);
        ax += (dq0.x - dr0.x) * n0; ay += (dq0.y - dr0.y) * n0;
    }
    float v0 = tanhf(ax * (1.f / 3.f) + b[c]);
    float v1 = tanhf(ay * (1.f / 3.f) + b[c + 1]);
    if (mode == 0) {
        v0 = fmaxf(v0, 0.f); v1 = fmaxf(v1, 0.f);
        Sb[(size_t)v * 64 + lane] = packbf2(v0, v1);
    } else {
        int g = batch[v];
        atomicAdd(pool + g * H + c,     v0);
        atomicAdd(pool + g * H + c + 1, v1);
    }
}

// ---------------- final: out[g] = [mean, rel_emb] @ lin_w + lin_b ----------------
__global__ void final_kernel(const float* __restrict__ pool, const float* __restrict__ cnt,
                             const float* __restrict__ rel_table, const int* __restrict__ rel_labels,
                             const float* __restrict__ lin_w, const float* __restrict__ lin_b,
                             float* __restrict__ out) {
    int g = blockIdx.x;
    int lane = threadIdx.x;   // 64
    float inv = 1.f / fmaxf(cnt[g], 1.f);
    const float* rrow = rel_table + (size_t)rel_labels[g] * H;
    float p0 = 0.f, p1 = 0.f;
    for (int c = lane; c < H; c += 64) {
        float m = pool[g * H + c] * inv;
        p0 += m * lin_w[c * 2 + 0];
        p1 += m * lin_w[c * 2 + 1];
        float rv = rrow[c];
        p0 += rv * lin_w[(H + c) * 2 + 0];
        p1 += rv * lin_w[(H + c) * 2 + 1];
    }
    for (int off = 32; off; off >>= 1) {
        p0 += __shfl_down(p0, off);
        p1 += __shfl_down(p1, off);
    }
    if (lane == 0) {
        out[g * 2 + 0] = p0 + lin_b[0];
        out[g * 2 + 1] = p1 + lin_b[1];
    }
}

extern "C" void kernel_launch(void* const* d_in, const int* in_sizes, int n_in,
                              void* d_out, int out_size, void* d_ws, size_t ws_size,
                              hipStream_t stream) {
    const float* x          = (const float*)d_in[0];
    const int*   ei         = (const int*)  d_in[1];
    const int*   etype      = (const int*)  d_in[2];
    const int*   batch      = (const int*)  d_in[3];
    const int*   rel_labels = (const int*)  d_in[4];
    const float* rel_table  = (const float*)d_in[6];
    const float* rge        = (const float*)d_in[7];
    const float* lin_w      = (const float*)d_in[26];
    const float* lin_b      = (const float*)d_in[27];
    float* out = (float*)d_out;

    // ---- workspace layout (regions padded to 16 B) ----
    float* ws       = (float*)d_ws;
    float* dinv_in  = ws;                    // N
    float* dinv_out = dinv_in + N_NODES;     // N
    float* pool     = dinv_out + N_NODES;    // NG*H
    float* cnt      = pool + NG * H;         // NG
    float* relA     = cnt + NG;              // 201*H
    float* rbuf     = relA + RELROWS * H;    // 200*H
    float* lwl      = rbuf + 200 * H;        // 3*H
    int*   rowptr   = (int*)(lwl + 3 * H);   // N+1 (pad to N+4)
    int*   rfill    = rowptr + N_NODES + 4;  // N
    int*   cnt_dst  = rfill + N_NODES;       // N
    int*   excl     = cnt_dst + N_NODES;     // N
    int*   bsum     = excl + N_NODES;        // SCAN_NB (pad 100)
    int*   boff     = bsum + 100;            // SCAN_NB (pad 100)
    int2*  csr_mn   = (int2*)(boff + 100);   // E int2
    unsigned short* QRf8 = (unsigned short*)(csr_mn + N_EDGES);   // 2N rows x 64 ushorts (fp8 pairs)
    unsigned* Sb    = (unsigned*)(QRf8 + (size_t)2 * N_NODES * 64);  // N x 64 uints (bf16 pairs)
    unsigned short* RWf8 = (unsigned short*)(Sb + (size_t)N_NODES * 64);  // 3 * 400 * 64 ushorts
    unsigned short* Bpack = RWf8 + (size_t)3 * 400 * 64;  // 9*16384 bf16

    hipMemsetAsync(dinv_in, 0, (size_t)(2 * N_NODES + NG * H + NG) * sizeof(float), stream);
    hipMemsetAsync(cnt_dst, 0, (size_t)N_NODES * sizeof(int), stream);

    deg_hist_kernel<<<(N_EDGES + 255) / 256, 256, 0, stream>>>(ei, dinv_in, dinv_out, cnt_dst);
    dinv_kernel    <<<(N_NODES + 255) / 256, 256, 0, stream>>>(dinv_in, dinv_out);
    scan1_kernel   <<<SCAN_NB, 1024, 0, stream>>>(cnt_dst, excl, bsum);
    scan2_kernel   <<<1, 128, 0, stream>>>(bsum, boff, rowptr);
    scan3_kernel   <<<SCAN_NB, 1024, 0, stream>>>(excl, boff, rowptr, rfill);
    fill_kernel    <<<(N_EDGES + 255) / 256, 256, 0, stream>>>(ei, etype, dinv_in, dinv_out,
                                                               rfill, csr_mn);
    cnt_bs_kernel  <<<NG / 64, 64, 0, stream>>>(batch, cnt);

    // pack all 9 weight matrices into MFMA B-frag order
    WPtrs wp;
    for (int l = 0; l < 3; l++) {
        wp.p[l * 3 + 0] = (const float*)d_in[8 + 6 * l + 0];  // wIn
        wp.p[l * 3 + 1] = (const float*)d_in[8 + 6 * l + 1];  // wOut
        wp.p[l * 3 + 2] = (const float*)d_in[8 + 6 * l + 2];  // wLoop
    }
    wpack_kernel<<<dim3(8, 9), 256, 0, stream>>>(wp, Bpack);

    // rel chain up-front
    for (int l = 0; l < 3; l++) {
        const float* wIn   = (const float*)d_in[8 + 6 * l + 0];
        const float* wOut  = (const float*)d_in[8 + 6 * l + 1];
        const float* wLoop = (const float*)d_in[8 + 6 * l + 2];
        const float* wRel  = (const float*)d_in[8 + 6 * l + 3];
        const float* lrel  = (const float*)d_in[8 + 6 * l + 4];
        rel_build_kernel<<<RELROWS, H, 0, stream>>>(rge, rbuf, lrel, relA, l + 1);
        rel_mm_kernel   <<<RELROWS, H, 0, stream>>>(relA, wIn, wOut, wRel, wLoop,
                                                    RWf8 + (size_t)l * 400 * 64,
                                                    rbuf, lwl + l * H);
    }

    // three conv layers
    int mm_grid = (N_NODES + MMB - 1) / MMB;
    for (int l = 0; l < 3; l++) {
        const float* bl = (const float*)d_in[8 + 6 * l + 5];
        mm_mfma_kernel<<<mm_grid, 256, 0, stream>>>(x, (const unsigned short*)Sb, (l == 0) ? 1 : 0,
                                                    Bpack + (size_t)l * 3 * 16384, lwl + l * H,
                                                    QRf8, (unsigned short*)Sb);
        gather_kernel<<<N_NODES / 4, 256, 0, stream>>>(rowptr, csr_mn,
                                                       QRf8, RWf8 + (size_t)l * 400 * 64, bl,
                                                       Sb, batch, pool, (l == 2) ? 1 : 0);
    }

    final_kernel<<<NG, 64, 0, stream>>>(pool, cnt, rel_table, rel_labels, lin_w, lin_b, out);
}

// Round 11
// 702.205 us; speedup vs baseline: 1.7695x; 1.0262x over previous
//
#include <hip/hip_runtime.h>
#include <hip/hip_bf16.h>
#include <math.h>

#define N_NODES 100000
#define N_EDGES 1000000
#define HALF_E  500000
#define H       128
#define NG      256
#define RELROWS 201
#define NH      (N_NODES * H)
#define SCAN_NB 98   // 98 * 1024 >= 100000
#define XPITCH  136  // 128 + 8 bf16 pad (breaks LDS bank aliasing)
#define MMB     64   // X rows per mm block

typedef __attribute__((ext_vector_type(8))) short bf16x8;
typedef __attribute__((ext_vector_type(4))) float f32x4;
typedef __attribute__((ext_vector_type(2))) float f32x2;

// ---- bf16 pack/unpack helpers (RNE) ----
__device__ __forceinline__ float bflo(unsigned p) { return __uint_as_float(p << 16); }
__device__ __forceinline__ float bfhi(unsigned p) { return __uint_as_float(p & 0xffff0000u); }
__device__ __forceinline__ unsigned packbf2(float a, float b) {
    unsigned ua = __float_as_uint(a), ub = __float_as_uint(b);
    ua = (ua + 0x7fffu + ((ua >> 16) & 1u)) >> 16;
    ub = (ub + 0x7fffu + ((ub >> 16) & 1u)) >> 16;
    return ua | (ub << 16);
}
__device__ __forceinline__ unsigned short packbf1(float a) {
    unsigned ua = __float_as_uint(a);
    return (unsigned short)((ua + 0x7fffu + ((ua >> 16) & 1u)) >> 16);
}

// ---- fp8 e4m3 (OCP) helpers ----
__device__ __forceinline__ float fp8_to_f32(unsigned v) {
    unsigned s = (v & 0x80u) << 24;
    float m = __uint_as_float((v & 0x7fu) << 20) * 0x1p+120f;
    return __uint_as_float(__float_as_uint(m) | s);
}

#if __has_builtin(__builtin_amdgcn_cvt_pk_f32_fp8)
__device__ __forceinline__ f32x2 f8pair(unsigned short p) {
    return __builtin_amdgcn_cvt_pk_f32_fp8((int)(unsigned)p, false);
}
#else
__device__ __forceinline__ f32x2 f8pair(unsigned short p) {
    f32x2 r;
    r.x = fp8_to_f32(p & 0xffu);
    r.y = fp8_to_f32((p >> 8) & 0xffu);
    return r;
}
#endif

#if __has_builtin(__builtin_amdgcn_cvt_pk_fp8_f32)
__device__ __forceinline__ unsigned short packfp8_2(float a, float b) {
    int v = __builtin_amdgcn_cvt_pk_fp8_f32(a, b, 0, false);
    return (unsigned short)(v & 0xffff);
}
#else
__device__ __forceinline__ unsigned fp8_enc1(float x) {
    float ax = fabsf(x);
    ax = fminf(ax, 448.f);
    unsigned sgn = (__float_as_uint(x) >> 24) & 0x80u;
    float sc = ax * 0x1p-120f;
    unsigned b = __float_as_uint(sc);
    if (b < 0x00080000u) return sgn;
    unsigned r = b + 0x7ffffu + ((b >> 20) & 1u);
    return sgn | (r >> 20);
}
__device__ __forceinline__ unsigned short packfp8_2(float a, float b) {
    return (unsigned short)(fp8_enc1(a) | (fp8_enc1(b) << 8));
}
#endif

// ---------------- degree (per-direction, over src) + dst histogram ----------------
__global__ void deg_hist_kernel(const int* __restrict__ ei, float* deg_in, float* deg_out,
                                int* __restrict__ cnt_dst) {
    int e = blockIdx.x * 256 + threadIdx.x;
    if (e >= N_EDGES) return;
    int src = ei[e];
    int dst = ei[N_EDGES + e];
    if (e < HALF_E) atomicAdd(deg_in + src, 1.0f);
    else            atomicAdd(deg_out + src, 1.0f);
    atomicAdd(cnt_dst + dst, 1);
}

__global__ void dinv_kernel(float* a, float* b) {
    int i = blockIdx.x * 256 + threadIdx.x;
    if (i >= N_NODES) return;
    float d = a[i]; a[i] = d > 0.f ? rsqrtf(d) : 0.f;
    d = b[i];       b[i] = d > 0.f ? rsqrtf(d) : 0.f;
}

// ---------------- 3-phase exclusive scan over cnt_dst ----------------
__global__ __launch_bounds__(1024) void scan1_kernel(const int* __restrict__ cnt,
                                                     int* __restrict__ excl,
                                                     int* __restrict__ bsum) {
    __shared__ int ps[1024];
    int t = threadIdx.x;
    int i = blockIdx.x * 1024 + t;
    int v = (i < N_NODES) ? cnt[i] : 0;
    ps[t] = v;
    __syncthreads();
    for (int off = 1; off < 1024; off <<= 1) {
        int u = (t >= off) ? ps[t - off] : 0;
        __syncthreads();
        ps[t] += u;
        __syncthreads();
    }
    if (i < N_NODES) excl[i] = ps[t] - v;
    if (t == 1023) bsum[blockIdx.x] = ps[t];
}

__global__ __launch_bounds__(128) void scan2_kernel(const int* __restrict__ bsum,
                                                    int* __restrict__ boff,
                                                    int* __restrict__ rowptr) {
    __shared__ int ps[128];
    int t = threadIdx.x;
    int v = (t < SCAN_NB) ? bsum[t] : 0;
    ps[t] = v;
    __syncthreads();
    for (int off = 1; off < 128; off <<= 1) {
        int u = (t >= off) ? ps[t - off] : 0;
        __syncthreads();
        ps[t] += u;
        __syncthreads();
    }
    if (t < SCAN_NB) boff[t] = ps[t] - v;
    if (t == 127) rowptr[N_NODES] = ps[t];
}

__global__ __launch_bounds__(1024) void scan3_kernel(const int* __restrict__ excl,
                                                     const int* __restrict__ boff,
                                                     int* __restrict__ rowptr,
                                                     int* __restrict__ rfill) {
    int t = threadIdx.x;
    int i = blockIdx.x * 1024 + t;
    if (i >= N_NODES) return;
    int r = excl[i] + boff[blockIdx.x];
    rowptr[i] = r;
    rfill[i] = r;
}

// ---------------- fill CSR: mn = { (src + dir*N) | ((typ + dir*200) << 18), bits(norm) } ----------------
__global__ void fill_kernel(const int* __restrict__ ei, const int* __restrict__ etype,
                            const float* __restrict__ dinv_in, const float* __restrict__ dinv_out,
                            int* __restrict__ rfill, int2* __restrict__ csr_mn) {
    int e = blockIdx.x * 256 + threadIdx.x;
    if (e >= N_EDGES) return;
    int s = ei[e], d = ei[N_EDGES + e];
    int t = etype[e];
    bool isin = (e < HALF_E);
    const float* dv = isin ? dinv_in : dinv_out;
    float nv = dv[s] * dv[d];
    int j = atomicAdd(rfill + d, 1);
    int src2 = s + (isin ? 0 : N_NODES);
    int typ2 = t + (isin ? 0 : 200);
    csr_mn[j] = make_int2(src2 | (typ2 << 18), __float_as_int(nv));
}

// ---------------- per-graph node counts via binary search (batch is sorted) ----------------
__global__ void cnt_bs_kernel(const int* __restrict__ batch, float* __restrict__ cnt) {
    int g = blockIdx.x * 64 + threadIdx.x;
    if (g >= NG) return;
    int lo = 0, hi = N_NODES;
    while (lo < hi) { int mid = (lo + hi) >> 1; if (batch[mid] < g) lo = mid + 1; else hi = mid; }
    int start = lo;
    lo = 0; hi = N_NODES;
    while (lo < hi) { int mid = (lo + hi) >> 1; if (batch[mid] < g + 1) lo = mid + 1; else hi = mid; }
    cnt[g] = (float)(lo - start);
}

// ---------------- rel chain (tiny) ----------------
__global__ void rel_build_kernel(const float* __restrict__ rge, const float* __restrict__ rbuf,
                                 const float* __restrict__ loop_rel, float* __restrict__ relA, int layer) {
    int i = blockIdx.x;      // 0..200
    int j = threadIdx.x;     // 0..127
    float v;
    if (i == 200)          v = loop_rel[j];
    else if (layer == 1)   v = (i < 100) ? rge[i * H + j] : -rge[(i - 100) * H + j];
    else                   v = rbuf[i * H + j];
    relA[i * H + j] = v;
}

// RWf8 layout per layer (fp8): rows 0..199 = rel@w_in, rows 200..399 = rel@w_out (64 ushorts/row)
__global__ void rel_mm_kernel(const float* __restrict__ relA,
                              const float* __restrict__ wIn, const float* __restrict__ wOut,
                              const float* __restrict__ wRel, const float* __restrict__ wLoop,
                              unsigned short* __restrict__ RWf8, float* __restrict__ rbuf,
                              float* __restrict__ lwl) {
    __shared__ float a[H];
    int i = blockIdx.x, j = threadIdx.x;
    a[j] = relA[i * H + j];
    __syncthreads();
    float s_in = 0.f, s_out = 0.f, s_rel = 0.f, s_loop = 0.f;
    for (int k = 0; k < H; k++) {
        float av = a[k];
        s_in  += av * wIn [k * H + j];
        s_out += av * wOut[k * H + j];
        s_rel += av * wRel[k * H + j];
        s_loop += av * wLoop[k * H + j];
    }
    float in_n  = __shfl_xor(s_in, 1);
    float out_n = __shfl_xor(s_out, 1);
    if (i < 200) {
        if ((j & 1) == 0) {
            RWf8[i * 64 + (j >> 1)]         = packfp8_2(s_in, in_n);
            RWf8[(200 + i) * 64 + (j >> 1)] = packfp8_2(s_out, out_n);
        }
        rbuf[i * H + j] = s_rel;
    }
    if (i == 200) lwl[j] = s_loop;
}

// ---------------- weight pre-pack into MFMA B-fragment order (bf16) ----------------
struct WPtrs { const float* p[9]; };
__global__ __launch_bounds__(256) void wpack_kernel(WPtrs wp, unsigned short* __restrict__ Bp) {
    int iw = blockIdx.y;  // l*3 + w
    const float* W = wp.p[iw];
    unsigned short* out = Bp + (size_t)iw * 16384;
    int t = blockIdx.x * 256 + threadIdx.x;   // 0..2047
    int nt = t >> 8, kk = (t >> 6) & 3, lane = t & 63;
    int n = nt * 16 + (lane & 15);
    int k0 = kk * 32 + (lane >> 4) * 8;
    unsigned p[4];
    for (int j = 0; j < 4; j++)
        p[j] = packbf2(W[(k0 + 2 * j) * H + n], W[(k0 + 2 * j + 1) * H + n]);
    *(uint4*)(out + ((size_t)(nt * 4 + kk) * 64 + lane) * 8) = make_uint4(p[0], p[1], p[2], p[3]);
}

// ---------------- MFMA node matmuls: Qf8=X@wIn, Rf8=X@wOut (fp8), Sb=X@wLoop - lwl (bf16) ----------------
// Epilogue: stage the 16x128 C-tile per wave in (reused) LDS, then fully-coalesced
// dwordx4 row-group stores (16 rows are contiguous; N % 16 == 0 so groups are all-or-nothing).
__global__ __launch_bounds__(256) void mm_mfma_kernel(const float* __restrict__ Xf,
                                                      const unsigned short* __restrict__ Xh,
                                                      int xf32,
                                                      const unsigned short* __restrict__ Bpack,
                                                      const float* __restrict__ lwl,
                                                      unsigned short* __restrict__ QRf8,
                                                      unsigned short* __restrict__ Sb) {
    __shared__ unsigned short xt[MMB * XPITCH];   // 17408 B; reused as per-wave staging after afrag load
    int tid = threadIdx.x;
    int row0 = blockIdx.x * MMB;
    int nrows = min(MMB, N_NODES - row0);
    if (xf32) {
        for (int t = 0; t < 8; t++) {
            int idx = tid + t * 256;                 // 2048 float4s
            int r = idx >> 5, c4 = (idx & 31) * 4;
            if (r < nrows) {
                float4 v = *(const float4*)(Xf + (size_t)(row0 + r) * H + c4);
                *(uint2*)(xt + r * XPITCH + c4) = make_uint2(packbf2(v.x, v.y), packbf2(v.z, v.w));
            }
        }
    } else {
        for (int t = 0; t < 4; t++) {
            int idx = tid + t * 256;                 // 1024 uint4s (8 bf16 each)
            int r = idx >> 4, c8 = (idx & 15) * 8;
            if (r < nrows)
                *(uint4*)(xt + r * XPITCH + c8) = *(const uint4*)(Xh + (size_t)(row0 + r) * H + c8);
        }
    }
    __syncthreads();

    int wave = tid >> 6, lane = tid & 63;
    int m0w = wave * 16;
    int q = lane >> 4, ml = lane & 15;
    bf16x8 afrag[4];
    for (int kk = 0; kk < 4; kk++)
        afrag[kk] = *(const bf16x8*)(xt + (m0w + ml) * XPITCH + kk * 32 + q * 8);
    __syncthreads();   // everyone done reading xt; safe to reuse as staging

    if (m0w + 16 > nrows) return;   // whole 16-row group out of range (N % 16 == 0)

    unsigned short* stg = xt + wave * 2176;   // 4352 B per wave (wave-private, no barriers needed)
    unsigned* stg32 = (unsigned*)stg;
    uint4* stg4 = (uint4*)stg;
    int grow0 = row0 + m0w;

    for (int w = 0; w < 3; w++) {
        for (int nt = 0; nt < 8; nt++) {
            const unsigned short* bp = Bpack + (((size_t)(w * 8 + nt) * 4) * 64 + lane) * 8;
            f32x4 acc = {0.f, 0.f, 0.f, 0.f};
            for (int kk = 0; kk < 4; kk++) {
                bf16x8 bfrag = *(const bf16x8*)(bp + (size_t)kk * 512);
                acc = __builtin_amdgcn_mfma_f32_16x16x32_bf16(afrag[kk], bfrag, acc, 0, 0, 0);
            }
            int col = nt * 16 + ml;
            if (w < 2) {
                // fp8 staging: 16 rows x 64 ushorts (row = 128 B)
                #pragma unroll
                for (int reg = 0; reg < 4; reg++) {
                    float v = acc[reg];
                    float vn = __shfl_xor(v, 1);
                    if ((lane & 1) == 0)
                        stg[(q * 4 + reg) * 64 + nt * 8 + (ml >> 1)] = packfp8_2(v, vn);
                }
            } else {
                // bf16 staging: 16 rows x 64 uints (row = 256 B)
                float sub = lwl[col];
                #pragma unroll
                for (int reg = 0; reg < 4; reg++) {
                    float v = acc[reg] - sub;
                    float vn = __shfl_xor(v, 1);
                    if ((lane & 1) == 0)
                        stg32[(q * 4 + reg) * 64 + nt * 8 + (ml >> 1)] = packbf2(v, vn);
                }
            }
        }
        // coalesced row-group store (rows grow0..grow0+15 contiguous)
        if (w < 2) {
            size_t rbase = (w == 0) ? 0 : (size_t)N_NODES;
            uint4* dst = (uint4*)QRf8 + (rbase + grow0) * 8;   // 128 B/row = 8 uint4
            dst[lane]      = stg4[lane];
            dst[lane + 64] = stg4[lane + 64];
        } else {
            uint4* dst = (uint4*)Sb + (size_t)grow0 * 16;      // 256 B/row = 16 uint4
            #pragma unroll
            for (int i = 0; i < 4; i++)
                dst[lane + 64 * i] = stg4[lane + 64 * i];
        }
    }
}

// ---------------- gather + combine: one wave per dst node, fp8 ushort loads, hw cvt, 8x unroll ----------------
__global__ __launch_bounds__(256, 8) void gather_kernel(const int* __restrict__ rowptr,
                                                        const int2* __restrict__ csr_mn,
                                                        const unsigned short* __restrict__ QRf8,
                                                        const unsigned short* __restrict__ RWf8,
                                                        const float* __restrict__ b,
                                                        unsigned* __restrict__ Sb,
                                                        const int* __restrict__ batch,
                                                        float* __restrict__ pool, int mode) {
    int v = blockIdx.x * 4 + (threadIdx.x >> 6);
    if (v >= N_NODES) return;
    int lane = threadIdx.x & 63;
    int c = lane * 2;
    int jb = rowptr[v], je = rowptr[v + 1];
    unsigned sv = Sb[(size_t)v * 64 + lane];
    float ax = bflo(sv), ay = bfhi(sv);   // loop term (bf16)
    int j = jb;
    for (; j + 7 < je; j += 8) {
        int2 mn[8];
        #pragma unroll
        for (int k = 0; k < 8; k++) mn[k] = csr_mn[j + k];
        unsigned short q[8], r[8];
        #pragma unroll
        for (int k = 0; k < 8; k++) {
            q[k] = QRf8[(size_t)(mn[k].x & 0x3FFFF) * 64 + lane];
            r[k] = RWf8[(size_t)((unsigned)mn[k].x >> 18) * 64 + lane];
        }
        #pragma unroll
        for (int k = 0; k < 8; k++) {
            float n = __int_as_float(mn[k].y);
            f32x2 dq = f8pair(q[k]);
            f32x2 dr = f8pair(r[k]);
            ax += (dq.x - dr.x) * n;
            ay += (dq.y - dr.y) * n;
        }
    }
    for (; j + 1 < je; j += 2) {
        int2 mn0 = csr_mn[j], mn1 = csr_mn[j + 1];
        unsigned short q0 = QRf8[(size_t)(mn0.x & 0x3FFFF) * 64 + lane];
        unsigned short r0 = RWf8[(size_t)((unsigned)mn0.x >> 18) * 64 + lane];
        unsigned short q1 = QRf8[(size_t)(mn1.x & 0x3FFFF) * 64 + lane];
        unsigned short r1 = RWf8[(size_t)((unsigned)mn1.x >> 18) * 64 + lane];
        float n0 = __int_as_float(mn0.y), n1 = __int_as_float(mn1.y);
        f32x2 dq0 = f8pair(q0), dr0 = f8pair(r0);
        f32x2 dq1 = f8pair(q1), dr1 = f8pair(r1);
        ax += (dq0.x - dr0.x) * n0; ay += (dq0.y - dr0.y) * n0;
        ax += (dq1.x - dr1.x) * n1; ay += (dq1.y - dr1.y) * n1;
    }
    if (j < je) {
        int2 mn0 = csr_mn[j];
        float n0 = __int_as_float(mn0.y);
        unsigned short q0 = QRf8[(size_t)(mn0.x & 0x3FFFF) * 64 + lane];
        unsigned short r0 = RWf8[(size_t)((unsigned)mn0.x >> 18) * 64 + lane];
        f32x2 dq0 = f8pair(q0), dr0 = f8pair(r0);
        ax += (dq0.x - dr0.x) * n0; ay += (dq0.y - dr0.y) * n0;
    }
    float v0 = tanhf(ax * (1.f / 3.f) + b[c]);
    float v1 = tanhf(ay * (1.f / 3.f) + b[c + 1]);
    if (mode == 0) {
        v0 = fmaxf(v0, 0.f); v1 = fmaxf(v1, 0.f);
        Sb[(size_t)v * 64 + lane] = packbf2(v0, v1);
    } else {
        int g = batch[v];
        atomicAdd(pool + g * H + c,     v0);
        atomicAdd(pool + g * H + c + 1, v1);
    }
}

// ---------------- final: out[g] = [mean, rel_emb] @ lin_w + lin_b ----------------
__global__ void final_kernel(const float* __restrict__ pool, const float* __restrict__ cnt,
                             const float* __restrict__ rel_table, const int* __restrict__ rel_labels,
                             const float* __restrict__ lin_w, const float* __restrict__ lin_b,
                             float* __restrict__ out) {
    int g = blockIdx.x;
    int lane = threadIdx.x;   // 64
    float inv = 1.f / fmaxf(cnt[g], 1.f);
    const float* rrow = rel_table + (size_t)rel_labels[g] * H;
    float p0 = 0.f, p1 = 0.f;
    for (int c = lane; c < H; c += 64) {
        float m = pool[g * H + c] * inv;
        p0 += m * lin_w[c * 2 + 0];
        p1 += m * lin_w[c * 2 + 1];
        float rv = rrow[c];
        p0 += rv * lin_w[(H + c) * 2 + 0];
        p1 += rv * lin_w[(H + c) * 2 + 1];
    }
    for (int off = 32; off; off >>= 1) {
        p0 += __shfl_down(p0, off);
        p1 += __shfl_down(p1, off);
    }
    if (lane == 0) {
        out[g * 2 + 0] = p0 + lin_b[0];
        out[g * 2 + 1] = p1 + lin_b[1];
    }
}

extern "C" void kernel_launch(void* const* d_in, const int* in_sizes, int n_in,
                              void* d_out, int out_size, void* d_ws, size_t ws_size,
                              hipStream_t stream) {
    const float* x          = (const float*)d_in[0];
    const int*   ei         = (const int*)  d_in[1];
    const int*   etype      = (const int*)  d_in[2];
    const int*   batch      = (const int*)  d_in[3];
    const int*   rel_labels = (const int*)  d_in[4];
    const float* rel_table  = (const float*)d_in[6];
    const float* rge        = (const float*)d_in[7];
    const float* lin_w      = (const float*)d_in[26];
    const float* lin_b      = (const float*)d_in[27];
    float* out = (float*)d_out;

    // ---- workspace layout (regions padded to 16 B) ----
    float* ws       = (float*)d_ws;
    float* dinv_in  = ws;                    // N
    float* dinv_out = dinv_in + N_NODES;     // N
    float* pool     = dinv_out + N_NODES;    // NG*H
    float* cnt      = pool + NG * H;         // NG
    float* relA     = cnt + NG;              // 201*H
    float* rbuf     = relA + RELROWS * H;    // 200*H
    float* lwl      = rbuf + 200 * H;        // 3*H
    int*   rowptr   = (int*)(lwl + 3 * H);   // N+1 (pad to N+4)
    int*   rfill    = rowptr + N_NODES + 4;  // N
    int*   cnt_dst  = rfill + N_NODES;       // N
    int*   excl     = cnt_dst + N_NODES;     // N
    int*   bsum     = excl + N_NODES;        // SCAN_NB (pad 100)
    int*   boff     = bsum + 100;            // SCAN_NB (pad 100)
    int2*  csr_mn   = (int2*)(boff + 100);   // E int2 (16 B aligned)
    unsigned short* QRf8 = (unsigned short*)(csr_mn + N_EDGES);   // 2N rows x 64 ushorts (fp8 pairs)
    unsigned* Sb    = (unsigned*)(QRf8 + (size_t)2 * N_NODES * 64);  // N x 64 uints (bf16 pairs)
    unsigned short* RWf8 = (unsigned short*)(Sb + (size_t)N_NODES * 64);  // 3 * 400 * 64 ushorts
    unsigned short* Bpack = RWf8 + (size_t)3 * 400 * 64;  // 9*16384 bf16

    hipMemsetAsync(dinv_in, 0, (size_t)(2 * N_NODES + NG * H + NG) * sizeof(float), stream);
    hipMemsetAsync(cnt_dst, 0, (size_t)N_NODES * sizeof(int), stream);

    deg_hist_kernel<<<(N_EDGES + 255) / 256, 256, 0, stream>>>(ei, dinv_in, dinv_out, cnt_dst);
    dinv_kernel    <<<(N_NODES + 255) / 256, 256, 0, stream>>>(dinv_in, dinv_out);
    scan1_kernel   <<<SCAN_NB, 1024, 0, stream>>>(cnt_dst, excl, bsum);
    scan2_kernel   <<<1, 128, 0, stream>>>(bsum, boff, rowptr);
    scan3_kernel   <<<SCAN_NB, 1024, 0, stream>>>(excl, boff, rowptr, rfill);
    fill_kernel    <<<(N_EDGES + 255) / 256, 256, 0, stream>>>(ei, etype, dinv_in, dinv_out,
                                                               rfill, csr_mn);
    cnt_bs_kernel  <<<NG / 64, 64, 0, stream>>>(batch, cnt);

    // pack all 9 weight matrices into MFMA B-frag order
    WPtrs wp;
    for (int l = 0; l < 3; l++) {
        wp.p[l * 3 + 0] = (const float*)d_in[8 + 6 * l + 0];  // wIn
        wp.p[l * 3 + 1] = (const float*)d_in[8 + 6 * l + 1];  // wOut
        wp.p[l * 3 + 2] = (const float*)d_in[8 + 6 * l + 2];  // wLoop
    }
    wpack_kernel<<<dim3(8, 9), 256, 0, stream>>>(wp, Bpack);

    // rel chain up-front
    for (int l = 0; l < 3; l++) {
        const float* wIn   = (const float*)d_in[8 + 6 * l + 0];
        const float* wOut  = (const float*)d_in[8 + 6 * l + 1];
        const float* wLoop = (const float*)d_in[8 + 6 * l + 2];
        const float* wRel  = (const float*)d_in[8 + 6 * l + 3];
        const float* lrel  = (const float*)d_in[8 + 6 * l + 4];
        rel_build_kernel<<<RELROWS, H, 0, stream>>>(rge, rbuf, lrel, relA, l + 1);
        rel_mm_kernel   <<<RELROWS, H, 0, stream>>>(relA, wIn, wOut, wRel, wLoop,
                                                    RWf8 + (size_t)l * 400 * 64,
                                                    rbuf, lwl + l * H);
    }

    // three conv layers
    int mm_grid = (N_NODES + MMB - 1) / MMB;
    for (int l = 0; l < 3; l++) {
        const float* bl = (const float*)d_in[8 + 6 * l + 5];
        mm_mfma_kernel<<<mm_grid, 256, 0, stream>>>(x, (const unsigned short*)Sb, (l == 0) ? 1 : 0,
                                                    Bpack + (size_t)l * 3 * 16384, lwl + l * H,
                                                    QRf8, (unsigned short*)Sb);
        gather_kernel<<<N_NODES / 4, 256, 0, stream>>>(rowptr, csr_mn,
                                                       QRf8, RWf8 + (size_t)l * 400 * 64, bl,
                                                       Sb, batch, pool, (l == 2) ? 1 : 0);
    }

    final_kernel<<<NG, 64, 0, stream>>>(pool, cnt, rel_table, rel_labels, lin_w, lin_b, out);
}

// Round 12
// 697.106 us; speedup vs baseline: 1.7825x; 1.0073x over previous
//
#include <hip/hip_runtime.h>
#include <hip/hip_bf16.h>
#include <math.h>

#define N_NODES 100000
#define N_EDGES 1000000
#define HALF_E  500000
#define H       128
#define NG      256
#define RELROWS 201
#define NH      (N_NODES * H)
#define SCAN_NB 98   // 98 * 1024 >= 100000
#define XPITCH  136  // 128 + 8 bf16 pad (breaks LDS bank aliasing)
#define MMB     64   // X rows per mm block

typedef __attribute__((ext_vector_type(8))) short bf16x8;
typedef __attribute__((ext_vector_type(4))) float f32x4;
typedef __attribute__((ext_vector_type(2))) float f32x2;

// ---- bf16 pack/unpack helpers (RNE) ----
__device__ __forceinline__ float bflo(unsigned p) { return __uint_as_float(p << 16); }
__device__ __forceinline__ float bfhi(unsigned p) { return __uint_as_float(p & 0xffff0000u); }
__device__ __forceinline__ unsigned packbf2(float a, float b) {
    unsigned ua = __float_as_uint(a), ub = __float_as_uint(b);
    ua = (ua + 0x7fffu + ((ua >> 16) & 1u)) >> 16;
    ub = (ub + 0x7fffu + ((ub >> 16) & 1u)) >> 16;
    return ua | (ub << 16);
}

// ---- fp8 e4m3 (OCP) helpers ----
__device__ __forceinline__ float fp8_to_f32(unsigned v) {
    unsigned s = (v & 0x80u) << 24;
    float m = __uint_as_float((v & 0x7fu) << 20) * 0x1p+120f;
    return __uint_as_float(__float_as_uint(m) | s);
}

#if __has_builtin(__builtin_amdgcn_cvt_pk_f32_fp8)
__device__ __forceinline__ f32x2 f8pair(unsigned short p) {
    return __builtin_amdgcn_cvt_pk_f32_fp8((int)(unsigned)p, false);
}
#else
__device__ __forceinline__ f32x2 f8pair(unsigned short p) {
    f32x2 r;
    r.x = fp8_to_f32(p & 0xffu);
    r.y = fp8_to_f32((p >> 8) & 0xffu);
    return r;
}
#endif

#if __has_builtin(__builtin_amdgcn_cvt_pk_fp8_f32)
__device__ __forceinline__ unsigned short packfp8_2(float a, float b) {
    int v = __builtin_amdgcn_cvt_pk_fp8_f32(a, b, 0, false);
    return (unsigned short)(v & 0xffff);
}
#else
__device__ __forceinline__ unsigned fp8_enc1(float x) {
    float ax = fabsf(x);
    ax = fminf(ax, 448.f);
    unsigned sgn = (__float_as_uint(x) >> 24) & 0x80u;
    float sc = ax * 0x1p-120f;
    unsigned b = __float_as_uint(sc);
    if (b < 0x00080000u) return sgn;
    unsigned r = b + 0x7ffffu + ((b >> 20) & 1u);
    return sgn | (r >> 20);
}
__device__ __forceinline__ unsigned short packfp8_2(float a, float b) {
    return (unsigned short)(fp8_enc1(a) | (fp8_enc1(b) << 8));
}
#endif

// ---------------- degree (per-direction, over src) + dst histogram ----------------
__global__ void deg_hist_kernel(const int* __restrict__ ei, float* deg_in, float* deg_out,
                                int* __restrict__ cnt_dst) {
    int e = blockIdx.x * 256 + threadIdx.x;
    if (e >= N_EDGES) return;
    int src = ei[e];
    int dst = ei[N_EDGES + e];
    if (e < HALF_E) atomicAdd(deg_in + src, 1.0f);
    else            atomicAdd(deg_out + src, 1.0f);
    atomicAdd(cnt_dst + dst, 1);
}

// ---------------- scan phase 1 (+ fused dinv) ----------------
__global__ __launch_bounds__(1024) void scan1_kernel(const int* __restrict__ cnt,
                                                     int* __restrict__ excl,
                                                     int* __restrict__ bsum,
                                                     float* deg_in, float* deg_out) {
    __shared__ int ps[1024];
    int t = threadIdx.x;
    int i = blockIdx.x * 1024 + t;
    // fused dinv (deg -> deg^-1/2); fill (later) consumes these
    if (i < N_NODES) {
        float d = deg_in[i];  deg_in[i]  = d > 0.f ? rsqrtf(d) : 0.f;
        d = deg_out[i];       deg_out[i] = d > 0.f ? rsqrtf(d) : 0.f;
    }
    int v = (i < N_NODES) ? cnt[i] : 0;
    ps[t] = v;
    __syncthreads();
    for (int off = 1; off < 1024; off <<= 1) {
        int u = (t >= off) ? ps[t - off] : 0;
        __syncthreads();
        ps[t] += u;
        __syncthreads();
    }
    if (i < N_NODES) excl[i] = ps[t] - v;
    if (t == 1023) bsum[blockIdx.x] = ps[t];
}

// ---------------- scan phase 2 (+ fused per-graph node counts via binary search) ----------------
__global__ __launch_bounds__(128) void scan2_kernel(const int* __restrict__ bsum,
                                                    int* __restrict__ boff,
                                                    int* __restrict__ rowptr,
                                                    const int* __restrict__ batch,
                                                    float* __restrict__ cnt_g) {
    __shared__ int ps[128];
    int t = threadIdx.x;
    // fused: per-graph counts (batch is sorted); only needed by final_kernel
    for (int g = t; g < NG; g += 128) {
        int lo = 0, hi = N_NODES;
        while (lo < hi) { int mid = (lo + hi) >> 1; if (batch[mid] < g) lo = mid + 1; else hi = mid; }
        int start = lo;
        lo = 0; hi = N_NODES;
        while (lo < hi) { int mid = (lo + hi) >> 1; if (batch[mid] < g + 1) lo = mid + 1; else hi = mid; }
        cnt_g[g] = (float)(lo - start);
    }
    int v = (t < SCAN_NB) ? bsum[t] : 0;
    ps[t] = v;
    __syncthreads();
    for (int off = 1; off < 128; off <<= 1) {
        int u = (t >= off) ? ps[t - off] : 0;
        __syncthreads();
        ps[t] += u;
        __syncthreads();
    }
    if (t < SCAN_NB) boff[t] = ps[t] - v;
    if (t == 127) rowptr[N_NODES] = ps[t];
}

__global__ __launch_bounds__(1024) void scan3_kernel(const int* __restrict__ excl,
                                                     const int* __restrict__ boff,
                                                     int* __restrict__ rowptr,
                                                     int* __restrict__ rfill) {
    int t = threadIdx.x;
    int i = blockIdx.x * 1024 + t;
    if (i >= N_NODES) return;
    int r = excl[i] + boff[blockIdx.x];
    rowptr[i] = r;
    rfill[i] = r;
}

// ---------------- fill CSR: mn = { (src + dir*N) | ((typ + dir*200) << 18), bits(norm) } ----------------
__global__ void fill_kernel(const int* __restrict__ ei, const int* __restrict__ etype,
                            const float* __restrict__ dinv_in, const float* __restrict__ dinv_out,
                            int* __restrict__ rfill, int2* __restrict__ csr_mn) {
    int e = blockIdx.x * 256 + threadIdx.x;
    if (e >= N_EDGES) return;
    int s = ei[e], d = ei[N_EDGES + e];
    int t = etype[e];
    bool isin = (e < HALF_E);
    const float* dv = isin ? dinv_in : dinv_out;
    float nv = dv[s] * dv[d];
    int j = atomicAdd(rfill + d, 1);
    int src2 = s + (isin ? 0 : N_NODES);
    int typ2 = t + (isin ? 0 : 200);
    csr_mn[j] = make_int2(src2 | (typ2 << 18), __float_as_int(nv));
}

// ---------------- rel chain (fused build+mm; one launch per layer) ----------------
// Input row i: layer 1 -> composed from rge/loop_rel; layers 2,3 -> rbuf row i (safe:
// block i reads only its own row into LDS before overwriting it after the barrier).
__global__ void rel_mm_kernel(const float* __restrict__ rge, const float* __restrict__ loop_rel,
                              int layer,
                              const float* __restrict__ wIn, const float* __restrict__ wOut,
                              const float* __restrict__ wRel, const float* __restrict__ wLoop,
                              unsigned short* __restrict__ RWf8, float* __restrict__ rbuf,
                              float* __restrict__ lwl) {
    __shared__ float a[H];
    int i = blockIdx.x, j = threadIdx.x;
    float v;
    if (i == 200)        v = loop_rel[j];
    else if (layer == 1) v = (i < 100) ? rge[i * H + j] : -rge[(i - 100) * H + j];
    else                 v = rbuf[i * H + j];
    a[j] = v;
    __syncthreads();
    float s_in = 0.f, s_out = 0.f, s_rel = 0.f, s_loop = 0.f;
    for (int k = 0; k < H; k++) {
        float av = a[k];
        s_in  += av * wIn [k * H + j];
        s_out += av * wOut[k * H + j];
        s_rel += av * wRel[k * H + j];
        s_loop += av * wLoop[k * H + j];
    }
    float in_n  = __shfl_xor(s_in, 1);
    float out_n = __shfl_xor(s_out, 1);
    if (i < 200) {
        if ((j & 1) == 0) {
            RWf8[i * 64 + (j >> 1)]         = packfp8_2(s_in, in_n);
            RWf8[(200 + i) * 64 + (j >> 1)] = packfp8_2(s_out, out_n);
        }
        rbuf[i * H + j] = s_rel;
    }
    if (i == 200) lwl[j] = s_loop;
}

// ---------------- weight pre-pack into MFMA B-fragment order (bf16) ----------------
struct WPtrs { const float* p[9]; };
__global__ __launch_bounds__(256) void wpack_kernel(WPtrs wp, unsigned short* __restrict__ Bp) {
    int iw = blockIdx.y;  // l*3 + w
    const float* W = wp.p[iw];
    unsigned short* out = Bp + (size_t)iw * 16384;
    int t = blockIdx.x * 256 + threadIdx.x;   // 0..2047
    int nt = t >> 8, kk = (t >> 6) & 3, lane = t & 63;
    int n = nt * 16 + (lane & 15);
    int k0 = kk * 32 + (lane >> 4) * 8;
    unsigned p[4];
    for (int j = 0; j < 4; j++)
        p[j] = packbf2(W[(k0 + 2 * j) * H + n], W[(k0 + 2 * j + 1) * H + n]);
    *(uint4*)(out + ((size_t)(nt * 4 + kk) * 64 + lane) * 8) = make_uint4(p[0], p[1], p[2], p[3]);
}

// ---------------- MFMA node matmuls: Qf8=X@wIn, Rf8=X@wOut (fp8), Sb=X@wLoop - lwl (bf16) ----------------
__global__ __launch_bounds__(256) void mm_mfma_kernel(const float* __restrict__ Xf,
                                                      const unsigned short* __restrict__ Xh,
                                                      int xf32,
                                                      const unsigned short* __restrict__ Bpack,
                                                      const float* __restrict__ lwl,
                                                      unsigned short* __restrict__ QRf8,
                                                      unsigned short* __restrict__ Sb) {
    __shared__ unsigned short xt[MMB * XPITCH];   // 17408 B; reused as per-wave staging after afrag load
    int tid = threadIdx.x;
    int row0 = blockIdx.x * MMB;
    int nrows = min(MMB, N_NODES - row0);
    if (xf32) {
        for (int t = 0; t < 8; t++) {
            int idx = tid + t * 256;                 // 2048 float4s
            int r = idx >> 5, c4 = (idx & 31) * 4;
            if (r < nrows) {
                float4 v = *(const float4*)(Xf + (size_t)(row0 + r) * H + c4);
                *(uint2*)(xt + r * XPITCH + c4) = make_uint2(packbf2(v.x, v.y), packbf2(v.z, v.w));
            }
        }
    } else {
        for (int t = 0; t < 4; t++) {
            int idx = tid + t * 256;                 // 1024 uint4s (8 bf16 each)
            int r = idx >> 4, c8 = (idx & 15) * 8;
            if (r < nrows)
                *(uint4*)(xt + r * XPITCH + c8) = *(const uint4*)(Xh + (size_t)(row0 + r) * H + c8);
        }
    }
    __syncthreads();

    int wave = tid >> 6, lane = tid & 63;
    int m0w = wave * 16;
    int q = lane >> 4, ml = lane & 15;
    bf16x8 afrag[4];
    for (int kk = 0; kk < 4; kk++)
        afrag[kk] = *(const bf16x8*)(xt + (m0w + ml) * XPITCH + kk * 32 + q * 8);
    __syncthreads();   // everyone done reading xt; safe to reuse as staging

    if (m0w + 16 > nrows) return;   // whole 16-row group out of range (N % 16 == 0)

    unsigned short* stg = xt + wave * 2176;   // 4352 B per wave (wave-private, no barriers needed)
    unsigned* stg32 = (unsigned*)stg;
    uint4* stg4 = (uint4*)stg;
    int grow0 = row0 + m0w;

    for (int w = 0; w < 3; w++) {
        for (int nt = 0; nt < 8; nt++) {
            const unsigned short* bp = Bpack + (((size_t)(w * 8 + nt) * 4) * 64 + lane) * 8;
            f32x4 acc = {0.f, 0.f, 0.f, 0.f};
            for (int kk = 0; kk < 4; kk++) {
                bf16x8 bfrag = *(const bf16x8*)(bp + (size_t)kk * 512);
                acc = __builtin_amdgcn_mfma_f32_16x16x32_bf16(afrag[kk], bfrag, acc, 0, 0, 0);
            }
            if (w < 2) {
                #pragma unroll
                for (int reg = 0; reg < 4; reg++) {
                    float v = acc[reg];
                    float vn = __shfl_xor(v, 1);
                    if ((lane & 1) == 0)
                        stg[(q * 4 + reg) * 64 + nt * 8 + (ml >> 1)] = packfp8_2(v, vn);
                }
            } else {
                float sub = lwl[nt * 16 + ml];
                #pragma unroll
                for (int reg = 0; reg < 4; reg++) {
                    float v = acc[reg] - sub;
                    float vn = __shfl_xor(v, 1);
                    if ((lane & 1) == 0)
                        stg32[(q * 4 + reg) * 64 + nt * 8 + (ml >> 1)] = packbf2(v, vn);
                }
            }
        }
        // coalesced row-group store (rows grow0..grow0+15 contiguous)
        if (w < 2) {
            size_t rbase = (w == 0) ? 0 : (size_t)N_NODES;
            uint4* dst = (uint4*)QRf8 + (rbase + grow0) * 8;   // 128 B/row = 8 uint4
            dst[lane]      = stg4[lane];
            dst[lane + 64] = stg4[lane + 64];
        } else {
            uint4* dst = (uint4*)Sb + (size_t)grow0 * 16;      // 256 B/row = 16 uint4
            #pragma unroll
            for (int i = 0; i < 4; i++)
                dst[lane + 64 * i] = stg4[lane + 64 * i];
        }
    }
}

// ---------------- gather + combine: one wave per dst node, fp8 ushort loads, hw cvt, 8x unroll ----------------
__global__ __launch_bounds__(256, 8) void gather_kernel(const int* __restrict__ rowptr,
                                                        const int2* __restrict__ csr_mn,
                                                        const unsigned short* __restrict__ QRf8,
                                                        const unsigned short* __restrict__ RWf8,
                                                        const float* __restrict__ b,
                                                        unsigned* __restrict__ Sb,
                                                        const int* __restrict__ batch,
                                                        float* __restrict__ pool, int mode) {
    int v = blockIdx.x * 4 + (threadIdx.x >> 6);
    if (v >= N_NODES) return;
    int lane = threadIdx.x & 63;
    int c = lane * 2;
    int jb = rowptr[v], je = rowptr[v + 1];
    unsigned sv = Sb[(size_t)v * 64 + lane];
    float ax = bflo(sv), ay = bfhi(sv);   // loop term (bf16)
    int j = jb;
    for (; j + 7 < je; j += 8) {
        int2 mn[8];
        #pragma unroll
        for (int k = 0; k < 8; k++) mn[k] = csr_mn[j + k];
        unsigned short q[8], r[8];
        #pragma unroll
        for (int k = 0; k < 8; k++) {
            q[k] = QRf8[(size_t)(mn[k].x & 0x3FFFF) * 64 + lane];
            r[k] = RWf8[(size_t)((unsigned)mn[k].x >> 18) * 64 + lane];
        }
        #pragma unroll
        for (int k = 0; k < 8; k++) {
            float n = __int_as_float(mn[k].y);
            f32x2 dq = f8pair(q[k]);
            f32x2 dr = f8pair(r[k]);
            ax += (dq.x - dr.x) * n;
            ay += (dq.y - dr.y) * n;
        }
    }
    for (; j + 1 < je; j += 2) {
        int2 mn0 = csr_mn[j], mn1 = csr_mn[j + 1];
        unsigned short q0 = QRf8[(size_t)(mn0.x & 0x3FFFF) * 64 + lane];
        unsigned short r0 = RWf8[(size_t)((unsigned)mn0.x >> 18) * 64 + lane];
        unsigned short q1 = QRf8[(size_t)(mn1.x & 0x3FFFF) * 64 + lane];
        unsigned short r1 = RWf8[(size_t)((unsigned)mn1.x >> 18) * 64 + lane];
        float n0 = __int_as_float(mn0.y), n1 = __int_as_float(mn1.y);
        f32x2 dq0 = f8pair(q0), dr0 = f8pair(r0);
        f32x2 dq1 = f8pair(q1), dr1 = f8pair(r1);
        ax += (dq0.x - dr0.x) * n0; ay += (dq0.y - dr0.y) * n0;
        ax += (dq1.x - dr1.x) * n1; ay += (dq1.y - dr1.y) * n1;
    }
    if (j < je) {
        int2 mn0 = csr_mn[j];
        float n0 = __int_as_float(mn0.y);
        unsigned short q0 = QRf8[(size_t)(mn0.x & 0x3FFFF) * 64 + lane];
        unsigned short r0 = RWf8[(size_t)((unsigned)mn0.x >> 18) * 64 + lane];
        f32x2 dq0 = f8pair(q0), dr0 = f8pair(r0);
        ax += (dq0.x - dr0.x) * n0; ay += (dq0.y - dr0.y) * n0;
    }
    float v0 = tanhf(ax * (1.f / 3.f) + b[c]);
    float v1 = tanhf(ay * (1.f / 3.f) + b[c + 1]);
    if (mode == 0) {
        v0 = fmaxf(v0, 0.f); v1 = fmaxf(v1, 0.f);
        Sb[(size_t)v * 64 + lane] = packbf2(v0, v1);
    } else {
        int g = batch[v];
        atomicAdd(pool + g * H + c,     v0);
        atomicAdd(pool + g * H + c + 1, v1);
    }
}

// ---------------- final: out[g] = [mean, rel_emb] @ lin_w + lin_b ----------------
__global__ void final_kernel(const float* __restrict__ pool, const float* __restrict__ cnt,
                             const float* __restrict__ rel_table, const int* __restrict__ rel_labels,
                             const float* __restrict__ lin_w, const float* __restrict__ lin_b,
                             float* __restrict__ out) {
    int g = blockIdx.x;
    int lane = threadIdx.x;   // 64
    float inv = 1.f / fmaxf(cnt[g], 1.f);
    const float* rrow = rel_table + (size_t)rel_labels[g] * H;
    float p0 = 0.f, p1 = 0.f;
    for (int c = lane; c < H; c += 64) {
        float m = pool[g * H + c] * inv;
        p0 += m * lin_w[c * 2 + 0];
        p1 += m * lin_w[c * 2 + 1];
        float rv = rrow[c];
        p0 += rv * lin_w[(H + c) * 2 + 0];
        p1 += rv * lin_w[(H + c) * 2 + 1];
    }
    for (int off = 32; off; off >>= 1) {
        p0 += __shfl_down(p0, off);
        p1 += __shfl_down(p1, off);
    }
    if (lane == 0) {
        out[g * 2 + 0] = p0 + lin_b[0];
        out[g * 2 + 1] = p1 + lin_b[1];
    }
}

extern "C" void kernel_launch(void* const* d_in, const int* in_sizes, int n_in,
                              void* d_out, int out_size, void* d_ws, size_t ws_size,
                              hipStream_t stream) {
    const float* x          = (const float*)d_in[0];
    const int*   ei         = (const int*)  d_in[1];
    const int*   etype      = (const int*)  d_in[2];
    const int*   batch      = (const int*)  d_in[3];
    const int*   rel_labels = (const int*)  d_in[4];
    const float* rel_table  = (const float*)d_in[6];
    const float* rge        = (const float*)d_in[7];
    const float* lin_w      = (const float*)d_in[26];
    const float* lin_b      = (const float*)d_in[27];
    float* out = (float*)d_out;

    // ---- workspace layout (regions padded to 16 B) ----
    float* ws       = (float*)d_ws;
    float* dinv_in  = ws;                    // N
    float* dinv_out = dinv_in + N_NODES;     // N
    float* pool     = dinv_out + N_NODES;    // NG*H
    float* cnt      = pool + NG * H;         // NG
    float* rbuf     = cnt + NG;              // 200*H
    float* lwl      = rbuf + 200 * H;        // 3*H
    int*   rowptr   = (int*)(lwl + 3 * H);   // N+1 (pad to N+4)
    int*   rfill    = rowptr + N_NODES + 4;  // N
    int*   cnt_dst  = rfill + N_NODES;       // N
    int*   excl     = cnt_dst + N_NODES;     // N
    int*   bsum     = excl + N_NODES;        // SCAN_NB (pad 100)
    int*   boff     = bsum + 100;            // SCAN_NB (pad 100)
    int2*  csr_mn   = (int2*)(boff + 100);   // E int2 (16 B aligned)
    unsigned short* QRf8 = (unsigned short*)(csr_mn + N_EDGES);   // 2N rows x 64 ushorts (fp8 pairs)
    unsigned* Sb    = (unsigned*)(QRf8 + (size_t)2 * N_NODES * 64);  // N x 64 uints (bf16 pairs)
    unsigned short* RWf8 = (unsigned short*)(Sb + (size_t)N_NODES * 64);  // 3 * 400 * 64 ushorts
    unsigned short* Bpack = RWf8 + (size_t)3 * 400 * 64;  // 9*16384 bf16

    hipMemsetAsync(dinv_in, 0, (size_t)(2 * N_NODES + NG * H + NG) * sizeof(float), stream);
    hipMemsetAsync(cnt_dst, 0, (size_t)N_NODES * sizeof(int), stream);

    deg_hist_kernel<<<(N_EDGES + 255) / 256, 256, 0, stream>>>(ei, dinv_in, dinv_out, cnt_dst);
    scan1_kernel   <<<SCAN_NB, 1024, 0, stream>>>(cnt_dst, excl, bsum, dinv_in, dinv_out);
    scan2_kernel   <<<1, 128, 0, stream>>>(bsum, boff, rowptr, batch, cnt);
    scan3_kernel   <<<SCAN_NB, 1024, 0, stream>>>(excl, boff, rowptr, rfill);
    fill_kernel    <<<(N_EDGES + 255) / 256, 256, 0, stream>>>(ei, etype, dinv_in, dinv_out,
                                                               rfill, csr_mn);

    // pack all 9 weight matrices into MFMA B-frag order
    WPtrs wp;
    for (int l = 0; l < 3; l++) {
        wp.p[l * 3 + 0] = (const float*)d_in[8 + 6 * l + 0];  // wIn
        wp.p[l * 3 + 1] = (const float*)d_in[8 + 6 * l + 1];  // wOut
        wp.p[l * 3 + 2] = (const float*)d_in[8 + 6 * l + 2];  // wLoop
    }
    wpack_kernel<<<dim3(8, 9), 256, 0, stream>>>(wp, Bpack);

    // rel chain up-front (fused build+mm, one launch per layer)
    for (int l = 0; l < 3; l++) {
        const float* wIn   = (const float*)d_in[8 + 6 * l + 0];
        const float* wOut  = (const float*)d_in[8 + 6 * l + 1];
        const float* wLoop = (const float*)d_in[8 + 6 * l + 2];
        const float* wRel  = (const float*)d_in[8 + 6 * l + 3];
        const float* lrel  = (const float*)d_in[8 + 6 * l + 4];
        rel_mm_kernel<<<RELROWS, H, 0, stream>>>(rge, lrel, l + 1, wIn, wOut, wRel, wLoop,
                                                 RWf8 + (size_t)l * 400 * 64,
                                                 rbuf, lwl + l * H);
    }

    // three conv layers
    int mm_grid = (N_NODES + MMB - 1) / MMB;
    for (int l = 0; l < 3; l++) {
        const float* bl = (const float*)d_in[8 + 6 * l + 5];
        mm_mfma_kernel<<<mm_grid, 256, 0, stream>>>(x, (const unsigned short*)Sb, (l == 0) ? 1 : 0,
                                                    Bpack + (size_t)l * 3 * 16384, lwl + l * H,
                                                    QRf8, (unsigned short*)Sb);
        gather_kernel<<<N_NODES / 4, 256, 0, stream>>>(rowptr, csr_mn,
                                                       QRf8, RWf8 + (size_t)l * 400 * 64, bl,
                                                       Sb, batch, pool, (l == 2) ? 1 : 0);
    }

    final_kernel<<<NG, 64, 0, stream>>>(pool, cnt, rel_table, rel_labels, lin_w, lin_b, out);
}